// Round 13
// baseline (447.468 us; speedup 1.0000x reference)
//
#include <hip/hip_runtime.h>
#include <math.h>

// FNO with global head, MI355X. Round 13:
//  - l3proj: per-h LDS banks s_b2[4] -> no cross-h WAR hazards, 4 independent
//    h-pipelines per wave (r11/r12 false-dependency-removal recipe).
//  - prep: zero+wprep+tabs merged into one dispatch.

#define TWO_PI_OVER_256 0.024543692606170259f

typedef short bf16x8 __attribute__((ext_vector_type(8)));
typedef float f32x4  __attribute__((ext_vector_type(4)));
typedef unsigned int u32;

__device__ __forceinline__ unsigned short bf16_rn(float f){
    unsigned int u = __float_as_uint(f);
    unsigned int r = (u + 0x7fffu + ((u >> 16) & 1u)) >> 16;
    return (unsigned short)r;
}
__device__ __forceinline__ float bf16_tf(unsigned short h){
    return __uint_as_float(((unsigned int)h) << 16);
}
__device__ __forceinline__ u32 pack_hilo(float f){
    unsigned short hi = bf16_rn(f);
    unsigned short lo = bf16_rn(f - bf16_tf(hi));
    return (u32)hi | ((u32)lo << 16);
}

__device__ __forceinline__ float gelu_f(float x){
    float x2 = x*x;
    float z2 = x*(1.5957691f + 0.07135482f*x2);
    float e = __expf(-z2);
    return x * __builtin_amdgcn_rcpf(1.0f + e);
}

__device__ __forceinline__ void build_tables(float* s_c, float* s_s){
    int t = threadIdx.x;
    if(t < 256){
        float ang = (float)t * TWO_PI_OVER_256;
        float sv, cv;
        sincosf(ang, &sv, &cv);
        s_c[t] = cv; s_s[t] = sv;
    }
}

__device__ __forceinline__ float2 dft_row(const float* s_row, const float* s_c, const float* s_s, int ky){
    float stc = s_c[(4*ky)&255], sts = s_s[(4*ky)&255];
    float rc = 1.0f, rs = 0.0f;
    float accR[4] = {0,0,0,0}, accI[4] = {0,0,0,0};
    const float4* row4 = (const float4*)s_row;
    #pragma unroll 4
    for(int m=0;m<64;m++){
        float4 v4 = row4[m];
        accR[0]+=v4.x*rc; accI[0]+=v4.x*rs;
        accR[1]+=v4.y*rc; accI[1]+=v4.y*rs;
        accR[2]+=v4.z*rc; accI[2]+=v4.z*rs;
        accR[3]+=v4.w*rc; accI[3]+=v4.w*rs;
        float nr = rc*stc + rs*sts;
        float ni = rs*stc - rc*sts;
        rc=nr; rs=ni;
    }
    float oR=0.0f, oI=0.0f;
    #pragma unroll
    for(int j=0;j<4;j++){
        float cj = s_c[(ky*j)&255], sj = s_s[(ky*j)&255];
        oR += accR[j]*cj + accI[j]*sj;
        oI += accI[j]*cj - accR[j]*sj;
    }
    return make_float2(oR, oI);
}

// Merged prep: blocks [0,2048) wprep, [2048,2272) tabs, [2272,2280) zero poolq.
__global__ __launch_bounds__(256) void fno_prep_k(const float* __restrict__ w1r, const float* __restrict__ w1i,
                                                  const float* __restrict__ w2r, const float* __restrict__ w2i,
                                                  float2* __restrict__ Wt2,
                                                  const float* __restrict__ skw, const float* __restrict__ W1,
                                                  unsigned short* __restrict__ Ep, unsigned short* __restrict__ Fp,
                                                  unsigned short* __restrict__ skA, unsigned short* __restrict__ W1A,
                                                  float* __restrict__ poolq){
    int blk = blockIdx.x;
    int t = threadIdx.x;
    if(blk < 2048){
        int l  = blk >> 9;
        int rem = blk & 511;
        int o = rem >> 5;
        int kxIdx = rem & 31;
        int ky = t >> 4, i = t & 15;
        int x = kxIdx & 15;
        const float* wr = (kxIdx < 16) ? w1r : w2r;
        const float* wi = (kxIdx < 16) ? w1i : w2i;
        int src = (((l*16 + i)*16 + o)*16 + x)*16 + ky;
        Wt2[((size_t)(l*16 + o)*512 + kxIdx*16 + ky)*16 + i] = make_float2(wr[src], wi[src]);
    } else if(blk < 2272){
        int idx = (blk - 2048)*256 + t;
        if(idx < 16384){
            int rem = idx;
            int pass = rem >> 13; rem &= 8191;
            int nt = rem >> 9; rem &= 511;
            int quad = rem >> 7;
            int col = (rem >> 3) & 15;
            int j = rem & 7;
            int k = quad*8 + j;
            int ky = k >> 1, ri = k & 1;
            int w = nt*16 + col;
            int ph = (ky*w) & 255;
            float sv, cv; sincosf((float)ph * TWO_PI_OVER_256, &sv, &cv);
            float val = ri ? -sv : cv;
            unsigned short hi = bf16_rn(val);
            Ep[idx] = pass ? bf16_rn(val - bf16_tf(hi)) : hi;
        } else if(idx < 16384 + 32768){
            int rem = idx - 16384;
            int pass = rem >> 14; rem &= 16383;
            int nt2 = rem >> 13; rem &= 8191;
            int s = rem >> 9; rem &= 511;
            int quad = rem >> 7;
            int col = (rem >> 3) & 15;
            int j = rem & 7;
            int wp = s*16 + quad*4 + (j >> 1);
            int kyRI = nt2*16 + col;
            int ky = kyRI >> 1, ri = kyRI & 1;
            int ph = (ky*wp) & 255;
            float sv, cv; sincosf((float)ph * TWO_PI_OVER_256, &sv, &cv);
            float val = ri ? -sv : cv;
            unsigned short hi = bf16_rn(val);
            Fp[idx - 16384] = pass ? bf16_rn(val - bf16_tf(hi)) : hi;
        } else if(idx < 16384 + 32768 + 4096){
            int rem = idx - (16384 + 32768);
            int l = rem >> 10;
            int part = (rem >> 9) & 1;
            int quad = (rem >> 7) & 3;
            int col = (rem >> 3) & 15;
            int j = rem & 7;
            int c = quad*4 + (j >> 1);
            float wv = skw[(l*16 + col)*16 + c];
            unsigned short hi = bf16_rn(wv);
            skA[rem] = part ? bf16_rn(wv - bf16_tf(hi)) : hi;
        } else if(idx < 16384 + 32768 + 4096 + 4096){
            int rem = idx - (16384 + 32768 + 4096);
            int kt = rem >> 9;
            int quad = (rem >> 7) & 3;
            int col = (rem >> 3) & 15;
            int j = rem & 7;
            float wv = W1[(kt*16 + col)*16 + (quad & 1)*8 + j];
            unsigned short hi = bf16_rn(wv);
            W1A[rem] = (quad >> 1) ? bf16_rn(wv - bf16_tf(hi)) : hi;
        }
    } else {
        int i = (blk - 2272)*256 + t;
        if(i < 2048) poolq[i] = 0.0f;
    }
}

// lift + row DFT + packed-v store. grid 4096 (b,h).
__global__ __launch_bounds__(256) void fno_liftf1_k(const float* __restrict__ x, const float* __restrict__ lw,
                                                    const float* __restrict__ lb, u32* __restrict__ vp,
                                                    float2* __restrict__ Fw){
    __shared__ float s_v[16*260];
    __shared__ float s_c[256], s_s[256];
    int t = threadIdx.x;
    build_tables(s_c, s_s);
    int b = blockIdx.x >> 8, h = blockIdx.x & 255;
    float xv = x[(b*256 + h)*256 + t];
    #pragma unroll
    for(int c=0;c<16;c++){
        float val = lw[c]*xv + lb[c];
        s_v[c*260 + t] = val;
    }
    __syncthreads();
    uint4* vp4 = (uint4*)(vp + (size_t)(b*256 + h)*4096);
    #pragma unroll
    for(int it=0;it<4;it++){
        int idx = it*256 + t;
        int px = idx >> 2, sg = idx & 3;
        int cg = sg ^ ((px >> 2) & 3);
        uint4 pk;
        pk.x = pack_hilo(s_v[(cg*4+0)*260 + px]);
        pk.y = pack_hilo(s_v[(cg*4+1)*260 + px]);
        pk.z = pack_hilo(s_v[(cg*4+2)*260 + px]);
        pk.w = pack_hilo(s_v[(cg*4+3)*260 + px]);
        vp4[idx] = pk;
    }
    int c = t >> 4, ky = t & 15;
    float2 r = dft_row(s_v + c*260, s_c, s_s, ky);
    Fw[((size_t)(b*16 + c)*256 + h)*16 + ky] = r;
}

// F2 quarter-split (f32). grid 1024.
__global__ __launch_bounds__(256) void fno_f2q_k(const float2* __restrict__ Fw, float2* __restrict__ vftp){
    __shared__ float2 s_fw[1024];
    __shared__ float2 s_red[2048];
    __shared__ float s_c[256], s_s[256];
    int t = threadIdx.x;
    build_tables(s_c, s_s);
    int bc = blockIdx.x >> 2, qr = blockIdx.x & 3;
    int qh = qr*64;
    {
        const float4* src = (const float4*)(Fw + (size_t)bc*4096 + qh*16);
        float4* d4 = (float4*)s_fw;
        for(int i=t;i<512;i+=256) d4[i] = src[i];
    }
    __syncthreads();
    int sub = t>>6, kyp = (t>>3)&7, kxg = t&7;
    int h0 = qh + sub*16;
    float rc[4], rs[4], stc[4], sts[4], aR[4][2], aI[4][2];
    #pragma unroll
    for(int p=0;p<4;p++){
        int kxIdx = kxg*4+p;
        int kx = kxIdx + ((kxIdx>=16)?224:0);
        int i0 = (kx*h0)&255;
        rc[p] = s_c[i0]; rs[p] = -s_s[i0];
        stc[p] = s_c[kx]; sts[p] = s_s[kx];
        aR[p][0]=aR[p][1]=aI[p][0]=aI[p][1]=0.0f;
    }
    #pragma unroll 4
    for(int hh=0; hh<16; hh++){
        float4 f = *(const float4*)&s_fw[(sub*16 + hh)*16 + kyp*2];
        #pragma unroll
        for(int p=0;p<4;p++){
            aR[p][0] += f.x*rc[p] - f.y*rs[p];
            aI[p][0] += f.x*rs[p] + f.y*rc[p];
            aR[p][1] += f.z*rc[p] - f.w*rs[p];
            aI[p][1] += f.z*rs[p] + f.w*rc[p];
            float nr = rc[p]*stc[p] + rs[p]*sts[p];
            float ni = rs[p]*stc[p] - rc[p]*sts[p];
            rc[p]=nr; rs[p]=ni;
        }
    }
    #pragma unroll
    for(int p=0;p<4;p++)
        #pragma unroll
        for(int y=0;y<2;y++)
            s_red[sub*512 + (kxg*4+p)*16 + kyp*2 + y] = make_float2(aR[p][y], aI[p][y]);
    __syncthreads();
    #pragma unroll
    for(int u=0;u<2;u++){
        int oidx = t*2 + u;
        float xr=0.0f, xi=0.0f;
        #pragma unroll
        for(int q=0;q<4;q++){ float2 pr = s_red[q*512 + oidx]; xr += pr.x; xi += pr.y; }
        vftp[(size_t)blockIdx.x*512 + oidx] = make_float2(xr, xi);
    }
}

// mix + I1 fused (f32), ky-half split. grid 512 = (b, o, kyh).
__global__ __launch_bounds__(256) void fno_mixi1_k(const float2* __restrict__ vftp, const float2* __restrict__ Wt2,
                                                   float2* __restrict__ Gh, int l){
    __shared__ float2 s_oft[256];     // [kx 32][kyl 8]
    __shared__ float s_c[256], s_s[256];
    int t = threadIdx.x;
    build_tables(s_c, s_s);
    int b = blockIdx.x >> 5;
    int o = (blockIdx.x >> 1) & 15;
    int kyh = blockIdx.x & 1;
    const float2* vb = vftp + (size_t)b*16*2048;
    const float2* wb = Wt2 + (size_t)(l*16 + o)*512*16;
    {
        int kx = t >> 3, kyl = t & 7;
        int m = kx*16 + kyh*8 + kyl;
        const float2* wm = wb + m*16;
        float aR=0.0f, aI=0.0f;
        #pragma unroll
        for(int i=0;i<16;i++){
            const float2* q0 = vb + i*2048 + m;
            float2 a0 = q0[0], a1 = q0[512], a2 = q0[1024], a3 = q0[1536];
            float vxr = a0.x+a1.x+a2.x+a3.x;
            float vxi = a0.y+a1.y+a2.y+a3.y;
            float2 wv = wm[i];
            aR += vxr*wv.x - vxi*wv.y;
            aI += vxr*wv.y + vxi*wv.x;
        }
        s_oft[t] = make_float2(aR, aI);
    }
    __syncthreads();
    int h = t;
    float hc = s_c[h], hs = s_s[h];
    float aR[8], aI[8];
    #pragma unroll
    for(int q=0;q<8;q++){ aR[q]=0.0f; aI[q]=0.0f; }
    float rc = 1.0f, rs = 0.0f;
    for(int kxIdx=0;kxIdx<16;kxIdx++){
        #pragma unroll
        for(int q=0;q<8;q++){
            float2 g = s_oft[kxIdx*8 + q];
            aR[q] += g.x*rc - g.y*rs;
            aI[q] += g.x*rs + g.y*rc;
        }
        float nr = rc*hc - rs*hs, ni = rc*hs + rs*hc;
        rc=nr; rs=ni;
    }
    { int i0 = (240*h)&255; rc = s_c[i0]; rs = s_s[i0]; }
    for(int kxIdx=16;kxIdx<32;kxIdx++){
        #pragma unroll
        for(int q=0;q<8;q++){
            float2 g = s_oft[kxIdx*8 + q];
            aR[q] += g.x*rc - g.y*rs;
            aI[q] += g.x*rs + g.y*rc;
        }
        float nr = rc*hc - rs*hs, ni = rc*hs + rs*hc;
        rc=nr; rs=ni;
    }
    const float inv = 1.0f/65536.0f;
    float4 pack[4];
    #pragma unroll
    for(int q=0;q<8;q+=2){
        float s0 = (kyh==0 && q==0) ? inv : 2.0f*inv;
        float s1 = 2.0f*inv;
        pack[q/2] = make_float4(aR[q]*s0, aI[q]*s0, aR[q+1]*s1, aI[q+1]*s1);
    }
    float4* d4 = (float4*)(Gh + ((size_t)(b*256 + h)*16 + o)*16 + kyh*8);
    #pragma unroll
    for(int q=0;q<4;q++) d4[q] = pack[q];
}

// G -> A-fragment, hi only.
__device__ __forceinline__ bf16x8 load_G_hi(const float2* __restrict__ Gh, int b, int h,
                                            int quad, int col){
    const float* gp = (const float*)Gh + (size_t)(b*256 + h)*512 + col*32 + quad*8;
    float4 g0 = *(const float4*)gp;
    float4 g1 = *(const float4*)(gp + 4);
    float g[8] = {g0.x,g0.y,g0.z,g0.w,g1.x,g1.y,g1.z,g1.w};
    bf16x8 ghi;
    #pragma unroll
    for(int j=0;j<8;j++) ghi[j] = (short)bf16_rn(g[j]);
    return ghi;
}

// Layer kernel (l<3). grid 1024 = (b, 4-row group), loop 4 h. (r12 form)
__global__ __launch_bounds__(256) void fno_layer_k(const float2* __restrict__ Gh, u32* __restrict__ vp,
                                                   const unsigned short* __restrict__ Ep,
                                                   const unsigned short* __restrict__ Fp,
                                                   const unsigned short* __restrict__ skA,
                                                   const float* __restrict__ skb,
                                                   float2* __restrict__ Fw, int l){
    __shared__ u32 s_hilo[16*260];      // 16.6KB [c][w] packed
    __shared__ float s_part4[4*2048];   // 32KB [hi2][(wave*2+nt2)*64+lane][4]
    int t = threadIdx.x;
    int wave = t >> 6, lane = t & 63, quad = lane >> 4, col = lane & 15;
    int b = blockIdx.x >> 6, hg = blockIdx.x & 63;

    bf16x8 a_whi = *(const bf16x8*)&skA[((l*2 + 0)*64 + lane)*8];
    float4 skb4 = *(const float4*)&skb[l*16 + quad*4];
    float bv[4] = {skb4.x, skb4.y, skb4.z, skb4.w};
    int qs = quad ^ ((col >> 2) & 3);

    for(int hi2=0; hi2<4; hi2++){
        int h = hg*4 + hi2;
        u32* vpb = vp + (size_t)(b*256 + h)*4096;
        bf16x8 ghi = load_G_hi(Gh, b, h, quad, col);
        #pragma unroll
        for(int i=0;i<4;i++){
            int nt = wave*4 + i;
            int w = nt*16 + col;
            bf16x8 bskip = *(const bf16x8*)&vpb[w*16 + qs*4];
            bf16x8 behi = *(const bf16x8*)&Ep[((0*16 + nt)*64 + lane)*8];
            f32x4 acc = {0.0f,0.0f,0.0f,0.0f};
            acc = __builtin_amdgcn_mfma_f32_16x16x32_bf16(a_whi, bskip, acc, 0,0,0);
            acc = __builtin_amdgcn_mfma_f32_16x16x32_bf16(ghi, behi, acc, 0,0,0);
            uint4 pk;
            u32* pkp = (u32*)&pk;
            #pragma unroll
            for(int r=0;r<4;r++){
                float val = gelu_f(acc[r] + bv[r]);
                int o = quad*4 + r;
                u32 p = pack_hilo(val);
                s_hilo[o*260 + w] = p;
                pkp[r] = p;
            }
            *(uint4*)&vpb[w*16 + qs*4] = pk;
        }
        // wave-local s_hilo tile: no barrier (r11/r12-validated)
        f32x4 facc[2];
        facc[0] = (f32x4){0,0,0,0}; facc[1] = (f32x4){0,0,0,0};
        #pragma unroll
        for(int si=0;si<4;si++){
            int s = wave*4 + si;
            bf16x8 af = *(const bf16x8*)&s_hilo[col*260 + s*16 + quad*4];
            #pragma unroll
            for(int nt2=0;nt2<2;nt2++){
                bf16x8 bhi = *(const bf16x8*)&Fp[(((0*2 + nt2)*16 + s)*64 + lane)*8];
                facc[nt2] = __builtin_amdgcn_mfma_f32_16x16x32_bf16(af, bhi, facc[nt2], 0,0,0);
            }
        }
        #pragma unroll
        for(int nt2=0;nt2<2;nt2++){
            float4 fv = {facc[nt2][0], facc[nt2][1], facc[nt2][2], facc[nt2][3]};
            *(float4*)&s_part4[hi2*2048 + ((wave*2 + nt2)*64 + lane)*4] = fv;
        }
    }
    __syncthreads();    // the only block-wide barrier
    {
        int c = t >> 4, jj = t & 15;
        int nt2 = jj >> 3, kyl = jj & 7;
        int ky = nt2*8 + kyl;
        int lidx = (c >> 2)*16 + kyl*2;
        int reg = c & 3;
        #pragma unroll
        for(int hi2=0;hi2<4;hi2++){
            float re = 0.0f, im = 0.0f;
            #pragma unroll
            for(int wv=0;wv<4;wv++){
                re += s_part4[hi2*2048 + ((wv*2 + nt2)*64 + lidx)*4 + reg];
                im += s_part4[hi2*2048 + ((wv*2 + nt2)*64 + lidx + 1)*4 + reg];
            }
            Fw[((size_t)(b*16 + c)*256 + hg*4 + hi2)*16 + ky] = make_float2(re, im);
        }
    }
}

// Layer-3 + projection fused. grid 1024 = (b, 4-row group), unrolled 4 h with
// per-h LDS banks (no cross-h WAR hazards -> 4 independent pipelines per wave).
__global__ __launch_bounds__(256) void fno_l3proj_k(const float2* __restrict__ Gh, const u32* __restrict__ vp,
                                                    const unsigned short* __restrict__ Ep,
                                                    const unsigned short* __restrict__ skA,
                                                    const float* __restrict__ skb,
                                                    const unsigned short* __restrict__ W1A,
                                                    const float* __restrict__ b1,
                                                    float* __restrict__ poolq){
    __shared__ unsigned short s_b2[4][4096];   // 32KB, one bank per h
    __shared__ float s_b1[128];
    __shared__ float s_red[128*5];
    int t = threadIdx.x;
    int wave = t >> 6, lane = t & 63, quad = lane >> 4, col = lane & 15;
    int b = blockIdx.x >> 6, hg = blockIdx.x & 63;

    if(t < 128) s_b1[t] = b1[t];
    bf16x8 a_whi = *(const bf16x8*)&skA[((3*2 + 0)*64 + lane)*8];
    float4 skb4 = *(const float4*)&skb[3*16 + quad*4];
    float bv[4] = {skb4.x, skb4.y, skb4.z, skb4.w};
    int qs = quad ^ ((col >> 2) & 3);
    __syncthreads();                       // s_b1 ready; no more barriers until reduce

    float pacc[8][4];
    #pragma unroll
    for(int kt=0;kt<8;kt++)
        #pragma unroll
        for(int r=0;r<4;r++) pacc[kt][r] = 0.0f;

    #pragma unroll
    for(int hi2=0; hi2<4; hi2++){
        int h = hg*4 + hi2;
        const u32* vpb = vp + (size_t)(b*256 + h)*4096;
        bf16x8 ghi = load_G_hi(Gh, b, h, quad, col);
        #pragma unroll
        for(int i=0;i<4;i++){
            int nt = wave*4 + i;
            int w = nt*16 + col;
            bf16x8 bskip = *(const bf16x8*)&vpb[w*16 + qs*4];
            bf16x8 behi = *(const bf16x8*)&Ep[((0*16 + nt)*64 + lane)*8];
            f32x4 acc = {0.0f,0.0f,0.0f,0.0f};
            acc = __builtin_amdgcn_mfma_f32_16x16x32_bf16(a_whi, bskip, acc, 0,0,0);
            acc = __builtin_amdgcn_mfma_f32_16x16x32_bf16(ghi, behi, acc, 0,0,0);
            #pragma unroll
            for(int r=0;r<2;r++){
                u32 p = (u32)bf16_rn(acc[2*r] + bv[2*r]) | ((u32)bf16_rn(acc[2*r+1] + bv[2*r+1]) << 16);
                *(u32*)&s_b2[hi2][w*16 + quad*4 + 2*r] = p;
            }
        }
        // wave-local: no __syncthreads
        bf16x8 bfrag[4];
        #pragma unroll
        for(int i=0;i<4;i++){
            int wt = wave*4 + i;
            bfrag[i] = *(const bf16x8*)&s_b2[hi2][(wt*16 + col)*16 + (quad & 1)*8];
        }
        #pragma unroll
        for(int kt=0;kt<8;kt++){
            bf16x8 w1 = *(const bf16x8*)&W1A[(kt*64 + lane)*8];
            float4 bias = *(const float4*)&s_b1[kt*16 + quad*4];
            #pragma unroll
            for(int i=0;i<4;i++){
                f32x4 d = {0.0f,0.0f,0.0f,0.0f};
                d = __builtin_amdgcn_mfma_f32_16x16x32_bf16(w1, bfrag[i], d, 0,0,0);
                pacc[kt][0] += gelu_f(d[0] + bias.x);
                pacc[kt][1] += gelu_f(d[1] + bias.y);
                pacc[kt][2] += gelu_f(d[2] + bias.z);
                pacc[kt][3] += gelu_f(d[3] + bias.w);
            }
        }
    }
    #pragma unroll
    for(int kt=0;kt<8;kt++){
        #pragma unroll
        for(int r=0;r<4;r++){
            float s = pacc[kt][r];
            s += __shfl_xor(s, 1);
            s += __shfl_xor(s, 2);
            s += __shfl_xor(s, 4);
            s += __shfl_xor(s, 8);
            if(col == 0) s_red[(kt*16 + quad*4 + r)*5 + wave] = s;
        }
    }
    __syncthreads();
    if(t < 128){
        float s = s_red[t*5+0] + s_red[t*5+1] + s_red[t*5+2] + s_red[t*5+3];
        atomicAdd(&poolq[b*128 + t], s);
    }
}

// head
__global__ __launch_bounds__(1024) void fno_head_k(const float* __restrict__ poolq, const float* __restrict__ W2,
                                                   const float* __restrict__ b2, const float* __restrict__ hw,
                                                   const float* __restrict__ hb, float* __restrict__ out){
    __shared__ float s_pool[16][68];
    int t = threadIdx.x;
    int b = t >> 6, j = t & 63;
    const float* pq = poolq + b*128;
    const float* w2 = W2 + j*128;
    float dot = 0.0f;
    for(int k=0;k<128;k++) dot += w2[k]*pq[k];
    s_pool[b][j] = b2[j] + dot*(1.0f/65536.0f);
    __syncthreads();
    if(t < 32){
        int bb = t >> 1, c2 = t & 1;
        float z = hb[c2];
        #pragma unroll
        for(int j2=0;j2<64;j2++) z += hw[c2*64 + j2]*s_pool[bb][j2];
        out[bb*2 + c2] = tanhf(z);
    }
}

extern "C" void kernel_launch(void* const* d_in, const int* in_sizes, int n_in,
                              void* d_out, int out_size, void* d_ws, size_t ws_size,
                              hipStream_t stream) {
    const float* x       = (const float*)d_in[0];
    const float* lift_w  = (const float*)d_in[1];
    const float* lift_b  = (const float*)d_in[2];
    const float* w1r     = (const float*)d_in[3];
    const float* w1i     = (const float*)d_in[4];
    const float* w2r     = (const float*)d_in[5];
    const float* w2i     = (const float*)d_in[6];
    const float* skip_w  = (const float*)d_in[7];
    const float* skip_b  = (const float*)d_in[8];
    const float* proj_w1 = (const float*)d_in[9];
    const float* proj_b1 = (const float*)d_in[10];
    const float* proj_w2 = (const float*)d_in[11];
    const float* proj_b2 = (const float*)d_in[12];
    const float* head_w  = (const float*)d_in[13];
    const float* head_b  = (const float*)d_in[14];
    float* out = (float*)d_out;

    u32*    vp   = (u32*)d_ws;                   // 16,777,216 u32 (packed hi|lo v)
    float2* Fw   = (float2*)(vp + 16777216);     // 1,048,576 float2
    float2* vftp = Fw  + 1048576;                // 524,288 float2
    float2* Gh   = vftp + 524288;                // 1,048,576 float2
    float2* Wt2  = Gh  + 1048576;                // 524,288 float2
    float*  poolq = (float*)(Wt2 + 524288);      // 2,048 floats
    unsigned short* Ep  = (unsigned short*)(poolq + 2048);   // 16,384 shorts
    unsigned short* Fp  = Ep + 16384;                        // 32,768 shorts
    unsigned short* skA = Fp + 32768;                        // 4,096 shorts
    unsigned short* W1A = skA + 4096;                        // 4,096 shorts

    fno_prep_k<<<2280, 256, 0, stream>>>(w1r, w1i, w2r, w2i, Wt2,
                                         skip_w, proj_w1, Ep, Fp, skA, W1A, poolq);
    fno_liftf1_k<<<4096, 256, 0, stream>>>(x, lift_w, lift_b, vp, Fw);

    for(int l=0; l<4; l++){
        fno_f2q_k<<<1024, 256, 0, stream>>>(Fw, vftp);
        fno_mixi1_k<<<512, 256, 0, stream>>>(vftp, Wt2, Gh, l);
        if(l < 3){
            fno_layer_k<<<1024, 256, 0, stream>>>(Gh, vp, Ep, Fp, skA, skip_b, Fw, l);
        } else {
            fno_l3proj_k<<<1024, 256, 0, stream>>>(Gh, vp, Ep, skA, skip_b, W1A, proj_b1, poolq);
        }
    }

    fno_head_k<<<1, 1024, 0, stream>>>(poolq, proj_w2, proj_b2, head_w, head_b, out);
}

// Round 14
// 402.645 us; speedup vs baseline: 1.1113x; 1.1113x over previous
//
#include <hip/hip_runtime.h>
#include <math.h>

// FNO with global head, MI355X. Round 14: r12 kernels + r13's merged prep.
// (r13's 4-bank l3proj unroll reverted: VGPR 92->256, scratch spills, FETCH 37->96MB.)

#define TWO_PI_OVER_256 0.024543692606170259f

typedef short bf16x8 __attribute__((ext_vector_type(8)));
typedef float f32x4  __attribute__((ext_vector_type(4)));
typedef unsigned int u32;

__device__ __forceinline__ unsigned short bf16_rn(float f){
    unsigned int u = __float_as_uint(f);
    unsigned int r = (u + 0x7fffu + ((u >> 16) & 1u)) >> 16;
    return (unsigned short)r;
}
__device__ __forceinline__ float bf16_tf(unsigned short h){
    return __uint_as_float(((unsigned int)h) << 16);
}
__device__ __forceinline__ u32 pack_hilo(float f){
    unsigned short hi = bf16_rn(f);
    unsigned short lo = bf16_rn(f - bf16_tf(hi));
    return (u32)hi | ((u32)lo << 16);
}

__device__ __forceinline__ float gelu_f(float x){
    float x2 = x*x;
    float z2 = x*(1.5957691f + 0.07135482f*x2);
    float e = __expf(-z2);
    return x * __builtin_amdgcn_rcpf(1.0f + e);
}

__device__ __forceinline__ void build_tables(float* s_c, float* s_s){
    int t = threadIdx.x;
    if(t < 256){
        float ang = (float)t * TWO_PI_OVER_256;
        float sv, cv;
        sincosf(ang, &sv, &cv);
        s_c[t] = cv; s_s[t] = sv;
    }
}

__device__ __forceinline__ float2 dft_row(const float* s_row, const float* s_c, const float* s_s, int ky){
    float stc = s_c[(4*ky)&255], sts = s_s[(4*ky)&255];
    float rc = 1.0f, rs = 0.0f;
    float accR[4] = {0,0,0,0}, accI[4] = {0,0,0,0};
    const float4* row4 = (const float4*)s_row;
    #pragma unroll 4
    for(int m=0;m<64;m++){
        float4 v4 = row4[m];
        accR[0]+=v4.x*rc; accI[0]+=v4.x*rs;
        accR[1]+=v4.y*rc; accI[1]+=v4.y*rs;
        accR[2]+=v4.z*rc; accI[2]+=v4.z*rs;
        accR[3]+=v4.w*rc; accI[3]+=v4.w*rs;
        float nr = rc*stc + rs*sts;
        float ni = rs*stc - rc*sts;
        rc=nr; rs=ni;
    }
    float oR=0.0f, oI=0.0f;
    #pragma unroll
    for(int j=0;j<4;j++){
        float cj = s_c[(ky*j)&255], sj = s_s[(ky*j)&255];
        oR += accR[j]*cj + accI[j]*sj;
        oI += accI[j]*cj - accR[j]*sj;
    }
    return make_float2(oR, oI);
}

// Merged prep: blocks [0,2048) wprep, [2048,2272) tabs, [2272,2280) zero poolq.
__global__ __launch_bounds__(256) void fno_prep_k(const float* __restrict__ w1r, const float* __restrict__ w1i,
                                                  const float* __restrict__ w2r, const float* __restrict__ w2i,
                                                  float2* __restrict__ Wt2,
                                                  const float* __restrict__ skw, const float* __restrict__ W1,
                                                  unsigned short* __restrict__ Ep, unsigned short* __restrict__ Fp,
                                                  unsigned short* __restrict__ skA, unsigned short* __restrict__ W1A,
                                                  float* __restrict__ poolq){
    int blk = blockIdx.x;
    int t = threadIdx.x;
    if(blk < 2048){
        int l  = blk >> 9;
        int rem = blk & 511;
        int o = rem >> 5;
        int kxIdx = rem & 31;
        int ky = t >> 4, i = t & 15;
        int x = kxIdx & 15;
        const float* wr = (kxIdx < 16) ? w1r : w2r;
        const float* wi = (kxIdx < 16) ? w1i : w2i;
        int src = (((l*16 + i)*16 + o)*16 + x)*16 + ky;
        Wt2[((size_t)(l*16 + o)*512 + kxIdx*16 + ky)*16 + i] = make_float2(wr[src], wi[src]);
    } else if(blk < 2272){
        int idx = (blk - 2048)*256 + t;
        if(idx < 16384){
            int rem = idx;
            int pass = rem >> 13; rem &= 8191;
            int nt = rem >> 9; rem &= 511;
            int quad = rem >> 7;
            int col = (rem >> 3) & 15;
            int j = rem & 7;
            int k = quad*8 + j;
            int ky = k >> 1, ri = k & 1;
            int w = nt*16 + col;
            int ph = (ky*w) & 255;
            float sv, cv; sincosf((float)ph * TWO_PI_OVER_256, &sv, &cv);
            float val = ri ? -sv : cv;
            unsigned short hi = bf16_rn(val);
            Ep[idx] = pass ? bf16_rn(val - bf16_tf(hi)) : hi;
        } else if(idx < 16384 + 32768){
            int rem = idx - 16384;
            int pass = rem >> 14; rem &= 16383;
            int nt2 = rem >> 13; rem &= 8191;
            int s = rem >> 9; rem &= 511;
            int quad = rem >> 7;
            int col = (rem >> 3) & 15;
            int j = rem & 7;
            int wp = s*16 + quad*4 + (j >> 1);
            int kyRI = nt2*16 + col;
            int ky = kyRI >> 1, ri = kyRI & 1;
            int ph = (ky*wp) & 255;
            float sv, cv; sincosf((float)ph * TWO_PI_OVER_256, &sv, &cv);
            float val = ri ? -sv : cv;
            unsigned short hi = bf16_rn(val);
            Fp[idx - 16384] = pass ? bf16_rn(val - bf16_tf(hi)) : hi;
        } else if(idx < 16384 + 32768 + 4096){
            int rem = idx - (16384 + 32768);
            int l = rem >> 10;
            int part = (rem >> 9) & 1;
            int quad = (rem >> 7) & 3;
            int col = (rem >> 3) & 15;
            int j = rem & 7;
            int c = quad*4 + (j >> 1);
            float wv = skw[(l*16 + col)*16 + c];
            unsigned short hi = bf16_rn(wv);
            skA[rem] = part ? bf16_rn(wv - bf16_tf(hi)) : hi;
        } else if(idx < 16384 + 32768 + 4096 + 4096){
            int rem = idx - (16384 + 32768 + 4096);
            int kt = rem >> 9;
            int quad = (rem >> 7) & 3;
            int col = (rem >> 3) & 15;
            int j = rem & 7;
            float wv = W1[(kt*16 + col)*16 + (quad & 1)*8 + j];
            unsigned short hi = bf16_rn(wv);
            W1A[rem] = (quad >> 1) ? bf16_rn(wv - bf16_tf(hi)) : hi;
        }
    } else {
        int i = (blk - 2272)*256 + t;
        if(i < 2048) poolq[i] = 0.0f;
    }
}

// lift + row DFT + packed-v store. grid 4096 (b,h).
__global__ __launch_bounds__(256) void fno_liftf1_k(const float* __restrict__ x, const float* __restrict__ lw,
                                                    const float* __restrict__ lb, u32* __restrict__ vp,
                                                    float2* __restrict__ Fw){
    __shared__ float s_v[16*260];
    __shared__ float s_c[256], s_s[256];
    int t = threadIdx.x;
    build_tables(s_c, s_s);
    int b = blockIdx.x >> 8, h = blockIdx.x & 255;
    float xv = x[(b*256 + h)*256 + t];
    #pragma unroll
    for(int c=0;c<16;c++){
        float val = lw[c]*xv + lb[c];
        s_v[c*260 + t] = val;
    }
    __syncthreads();
    uint4* vp4 = (uint4*)(vp + (size_t)(b*256 + h)*4096);
    #pragma unroll
    for(int it=0;it<4;it++){
        int idx = it*256 + t;
        int px = idx >> 2, sg = idx & 3;
        int cg = sg ^ ((px >> 2) & 3);
        uint4 pk;
        pk.x = pack_hilo(s_v[(cg*4+0)*260 + px]);
        pk.y = pack_hilo(s_v[(cg*4+1)*260 + px]);
        pk.z = pack_hilo(s_v[(cg*4+2)*260 + px]);
        pk.w = pack_hilo(s_v[(cg*4+3)*260 + px]);
        vp4[idx] = pk;
    }
    int c = t >> 4, ky = t & 15;
    float2 r = dft_row(s_v + c*260, s_c, s_s, ky);
    Fw[((size_t)(b*16 + c)*256 + h)*16 + ky] = r;
}

// F2 quarter-split (f32). grid 1024.
__global__ __launch_bounds__(256) void fno_f2q_k(const float2* __restrict__ Fw, float2* __restrict__ vftp){
    __shared__ float2 s_fw[1024];
    __shared__ float2 s_red[2048];
    __shared__ float s_c[256], s_s[256];
    int t = threadIdx.x;
    build_tables(s_c, s_s);
    int bc = blockIdx.x >> 2, qr = blockIdx.x & 3;
    int qh = qr*64;
    {
        const float4* src = (const float4*)(Fw + (size_t)bc*4096 + qh*16);
        float4* d4 = (float4*)s_fw;
        for(int i=t;i<512;i+=256) d4[i] = src[i];
    }
    __syncthreads();
    int sub = t>>6, kyp = (t>>3)&7, kxg = t&7;
    int h0 = qh + sub*16;
    float rc[4], rs[4], stc[4], sts[4], aR[4][2], aI[4][2];
    #pragma unroll
    for(int p=0;p<4;p++){
        int kxIdx = kxg*4+p;
        int kx = kxIdx + ((kxIdx>=16)?224:0);
        int i0 = (kx*h0)&255;
        rc[p] = s_c[i0]; rs[p] = -s_s[i0];
        stc[p] = s_c[kx]; sts[p] = s_s[kx];
        aR[p][0]=aR[p][1]=aI[p][0]=aI[p][1]=0.0f;
    }
    #pragma unroll 4
    for(int hh=0; hh<16; hh++){
        float4 f = *(const float4*)&s_fw[(sub*16 + hh)*16 + kyp*2];
        #pragma unroll
        for(int p=0;p<4;p++){
            aR[p][0] += f.x*rc[p] - f.y*rs[p];
            aI[p][0] += f.x*rs[p] + f.y*rc[p];
            aR[p][1] += f.z*rc[p] - f.w*rs[p];
            aI[p][1] += f.z*rs[p] + f.w*rc[p];
            float nr = rc[p]*stc[p] + rs[p]*sts[p];
            float ni = rs[p]*stc[p] - rc[p]*sts[p];
            rc[p]=nr; rs[p]=ni;
        }
    }
    #pragma unroll
    for(int p=0;p<4;p++)
        #pragma unroll
        for(int y=0;y<2;y++)
            s_red[sub*512 + (kxg*4+p)*16 + kyp*2 + y] = make_float2(aR[p][y], aI[p][y]);
    __syncthreads();
    #pragma unroll
    for(int u=0;u<2;u++){
        int oidx = t*2 + u;
        float xr=0.0f, xi=0.0f;
        #pragma unroll
        for(int q=0;q<4;q++){ float2 pr = s_red[q*512 + oidx]; xr += pr.x; xi += pr.y; }
        vftp[(size_t)blockIdx.x*512 + oidx] = make_float2(xr, xi);
    }
}

// mix + I1 fused (f32), ky-half split. grid 512 = (b, o, kyh).
__global__ __launch_bounds__(256) void fno_mixi1_k(const float2* __restrict__ vftp, const float2* __restrict__ Wt2,
                                                   float2* __restrict__ Gh, int l){
    __shared__ float2 s_oft[256];     // [kx 32][kyl 8]
    __shared__ float s_c[256], s_s[256];
    int t = threadIdx.x;
    build_tables(s_c, s_s);
    int b = blockIdx.x >> 5;
    int o = (blockIdx.x >> 1) & 15;
    int kyh = blockIdx.x & 1;
    const float2* vb = vftp + (size_t)b*16*2048;
    const float2* wb = Wt2 + (size_t)(l*16 + o)*512*16;
    {
        int kx = t >> 3, kyl = t & 7;
        int m = kx*16 + kyh*8 + kyl;
        const float2* wm = wb + m*16;
        float aR=0.0f, aI=0.0f;
        #pragma unroll
        for(int i=0;i<16;i++){
            const float2* q0 = vb + i*2048 + m;
            float2 a0 = q0[0], a1 = q0[512], a2 = q0[1024], a3 = q0[1536];
            float vxr = a0.x+a1.x+a2.x+a3.x;
            float vxi = a0.y+a1.y+a2.y+a3.y;
            float2 wv = wm[i];
            aR += vxr*wv.x - vxi*wv.y;
            aI += vxr*wv.y + vxi*wv.x;
        }
        s_oft[t] = make_float2(aR, aI);
    }
    __syncthreads();
    int h = t;
    float hc = s_c[h], hs = s_s[h];
    float aR[8], aI[8];
    #pragma unroll
    for(int q=0;q<8;q++){ aR[q]=0.0f; aI[q]=0.0f; }
    float rc = 1.0f, rs = 0.0f;
    for(int kxIdx=0;kxIdx<16;kxIdx++){
        #pragma unroll
        for(int q=0;q<8;q++){
            float2 g = s_oft[kxIdx*8 + q];
            aR[q] += g.x*rc - g.y*rs;
            aI[q] += g.x*rs + g.y*rc;
        }
        float nr = rc*hc - rs*hs, ni = rc*hs + rs*hc;
        rc=nr; rs=ni;
    }
    { int i0 = (240*h)&255; rc = s_c[i0]; rs = s_s[i0]; }
    for(int kxIdx=16;kxIdx<32;kxIdx++){
        #pragma unroll
        for(int q=0;q<8;q++){
            float2 g = s_oft[kxIdx*8 + q];
            aR[q] += g.x*rc - g.y*rs;
            aI[q] += g.x*rs + g.y*rc;
        }
        float nr = rc*hc - rs*hs, ni = rc*hs + rs*hc;
        rc=nr; rs=ni;
    }
    const float inv = 1.0f/65536.0f;
    float4 pack[4];
    #pragma unroll
    for(int q=0;q<8;q+=2){
        float s0 = (kyh==0 && q==0) ? inv : 2.0f*inv;
        float s1 = 2.0f*inv;
        pack[q/2] = make_float4(aR[q]*s0, aI[q]*s0, aR[q+1]*s1, aI[q+1]*s1);
    }
    float4* d4 = (float4*)(Gh + ((size_t)(b*256 + h)*16 + o)*16 + kyh*8);
    #pragma unroll
    for(int q=0;q<4;q++) d4[q] = pack[q];
}

// G -> A-fragment, hi only.
__device__ __forceinline__ bf16x8 load_G_hi(const float2* __restrict__ Gh, int b, int h,
                                            int quad, int col){
    const float* gp = (const float*)Gh + (size_t)(b*256 + h)*512 + col*32 + quad*8;
    float4 g0 = *(const float4*)gp;
    float4 g1 = *(const float4*)(gp + 4);
    float g[8] = {g0.x,g0.y,g0.z,g0.w,g1.x,g1.y,g1.z,g1.w};
    bf16x8 ghi;
    #pragma unroll
    for(int j=0;j<8;j++) ghi[j] = (short)bf16_rn(g[j]);
    return ghi;
}

// Layer kernel (l<3). grid 1024 = (b, 4-row group), loop 4 h. (r12 form)
__global__ __launch_bounds__(256) void fno_layer_k(const float2* __restrict__ Gh, u32* __restrict__ vp,
                                                   const unsigned short* __restrict__ Ep,
                                                   const unsigned short* __restrict__ Fp,
                                                   const unsigned short* __restrict__ skA,
                                                   const float* __restrict__ skb,
                                                   float2* __restrict__ Fw, int l){
    __shared__ u32 s_hilo[16*260];      // 16.6KB [c][w] packed
    __shared__ float s_part4[4*2048];   // 32KB [hi2][(wave*2+nt2)*64+lane][4]
    int t = threadIdx.x;
    int wave = t >> 6, lane = t & 63, quad = lane >> 4, col = lane & 15;
    int b = blockIdx.x >> 6, hg = blockIdx.x & 63;

    bf16x8 a_whi = *(const bf16x8*)&skA[((l*2 + 0)*64 + lane)*8];
    float4 skb4 = *(const float4*)&skb[l*16 + quad*4];
    float bv[4] = {skb4.x, skb4.y, skb4.z, skb4.w};
    int qs = quad ^ ((col >> 2) & 3);

    for(int hi2=0; hi2<4; hi2++){
        int h = hg*4 + hi2;
        u32* vpb = vp + (size_t)(b*256 + h)*4096;
        bf16x8 ghi = load_G_hi(Gh, b, h, quad, col);
        #pragma unroll
        for(int i=0;i<4;i++){
            int nt = wave*4 + i;
            int w = nt*16 + col;
            bf16x8 bskip = *(const bf16x8*)&vpb[w*16 + qs*4];
            bf16x8 behi = *(const bf16x8*)&Ep[((0*16 + nt)*64 + lane)*8];
            f32x4 acc = {0.0f,0.0f,0.0f,0.0f};
            acc = __builtin_amdgcn_mfma_f32_16x16x32_bf16(a_whi, bskip, acc, 0,0,0);
            acc = __builtin_amdgcn_mfma_f32_16x16x32_bf16(ghi, behi, acc, 0,0,0);
            uint4 pk;
            u32* pkp = (u32*)&pk;
            #pragma unroll
            for(int r=0;r<4;r++){
                float val = gelu_f(acc[r] + bv[r]);
                int o = quad*4 + r;
                u32 p = pack_hilo(val);
                s_hilo[o*260 + w] = p;
                pkp[r] = p;
            }
            *(uint4*)&vpb[w*16 + qs*4] = pk;
        }
        // wave-local s_hilo tile: no barrier (r11/r12-validated)
        f32x4 facc[2];
        facc[0] = (f32x4){0,0,0,0}; facc[1] = (f32x4){0,0,0,0};
        #pragma unroll
        for(int si=0;si<4;si++){
            int s = wave*4 + si;
            bf16x8 af = *(const bf16x8*)&s_hilo[col*260 + s*16 + quad*4];
            #pragma unroll
            for(int nt2=0;nt2<2;nt2++){
                bf16x8 bhi = *(const bf16x8*)&Fp[(((0*2 + nt2)*16 + s)*64 + lane)*8];
                facc[nt2] = __builtin_amdgcn_mfma_f32_16x16x32_bf16(af, bhi, facc[nt2], 0,0,0);
            }
        }
        #pragma unroll
        for(int nt2=0;nt2<2;nt2++){
            float4 fv = {facc[nt2][0], facc[nt2][1], facc[nt2][2], facc[nt2][3]};
            *(float4*)&s_part4[hi2*2048 + ((wave*2 + nt2)*64 + lane)*4] = fv;
        }
    }
    __syncthreads();    // the only block-wide barrier
    {
        int c = t >> 4, jj = t & 15;
        int nt2 = jj >> 3, kyl = jj & 7;
        int ky = nt2*8 + kyl;
        int lidx = (c >> 2)*16 + kyl*2;
        int reg = c & 3;
        #pragma unroll
        for(int hi2=0;hi2<4;hi2++){
            float re = 0.0f, im = 0.0f;
            #pragma unroll
            for(int wv=0;wv<4;wv++){
                re += s_part4[hi2*2048 + ((wv*2 + nt2)*64 + lidx)*4 + reg];
                im += s_part4[hi2*2048 + ((wv*2 + nt2)*64 + lidx + 1)*4 + reg];
            }
            Fw[((size_t)(b*16 + c)*256 + hg*4 + hi2)*16 + ky] = make_float2(re, im);
        }
    }
}

// Layer-3 + projection fused. grid 1024 = (b, 4-row group), loop 4 h. (r12 form)
__global__ __launch_bounds__(256) void fno_l3proj_k(const float2* __restrict__ Gh, const u32* __restrict__ vp,
                                                    const unsigned short* __restrict__ Ep,
                                                    const unsigned short* __restrict__ skA,
                                                    const float* __restrict__ skb,
                                                    const unsigned short* __restrict__ W1A,
                                                    const float* __restrict__ b1,
                                                    float* __restrict__ poolq){
    __shared__ unsigned short s_b2[4096];   // 8KB v_new bf16 [px][c], wave-local tiles
    __shared__ float s_b1[128];
    __shared__ float s_red[128*5];
    int t = threadIdx.x;
    int wave = t >> 6, lane = t & 63, quad = lane >> 4, col = lane & 15;
    int b = blockIdx.x >> 6, hg = blockIdx.x & 63;

    if(t < 128) s_b1[t] = b1[t];
    bf16x8 a_whi = *(const bf16x8*)&skA[((3*2 + 0)*64 + lane)*8];
    float4 skb4 = *(const float4*)&skb[3*16 + quad*4];
    float bv[4] = {skb4.x, skb4.y, skb4.z, skb4.w};
    int qs = quad ^ ((col >> 2) & 3);
    __syncthreads();                       // s_b1 ready; no more barriers until reduce

    float pacc[8][4];
    #pragma unroll
    for(int kt=0;kt<8;kt++)
        #pragma unroll
        for(int r=0;r<4;r++) pacc[kt][r] = 0.0f;

    for(int hi2=0; hi2<4; hi2++){
        int h = hg*4 + hi2;
        const u32* vpb = vp + (size_t)(b*256 + h)*4096;
        bf16x8 ghi = load_G_hi(Gh, b, h, quad, col);
        #pragma unroll
        for(int i=0;i<4;i++){
            int nt = wave*4 + i;
            int w = nt*16 + col;
            bf16x8 bskip = *(const bf16x8*)&vpb[w*16 + qs*4];
            bf16x8 behi = *(const bf16x8*)&Ep[((0*16 + nt)*64 + lane)*8];
            f32x4 acc = {0.0f,0.0f,0.0f,0.0f};
            acc = __builtin_amdgcn_mfma_f32_16x16x32_bf16(a_whi, bskip, acc, 0,0,0);
            acc = __builtin_amdgcn_mfma_f32_16x16x32_bf16(ghi, behi, acc, 0,0,0);
            #pragma unroll
            for(int r=0;r<2;r++){
                u32 p = (u32)bf16_rn(acc[2*r] + bv[2*r]) | ((u32)bf16_rn(acc[2*r+1] + bv[2*r+1]) << 16);
                *(u32*)&s_b2[w*16 + quad*4 + 2*r] = p;
            }
        }
        // wave-local: no __syncthreads
        bf16x8 bfrag[4];
        #pragma unroll
        for(int i=0;i<4;i++){
            int wt = wave*4 + i;
            bfrag[i] = *(const bf16x8*)&s_b2[(wt*16 + col)*16 + (quad & 1)*8];
        }
        #pragma unroll
        for(int kt=0;kt<8;kt++){
            bf16x8 w1 = *(const bf16x8*)&W1A[(kt*64 + lane)*8];
            float4 bias = *(const float4*)&s_b1[kt*16 + quad*4];
            #pragma unroll
            for(int i=0;i<4;i++){
                f32x4 d = {0.0f,0.0f,0.0f,0.0f};
                d = __builtin_amdgcn_mfma_f32_16x16x32_bf16(w1, bfrag[i], d, 0,0,0);
                pacc[kt][0] += gelu_f(d[0] + bias.x);
                pacc[kt][1] += gelu_f(d[1] + bias.y);
                pacc[kt][2] += gelu_f(d[2] + bias.z);
                pacc[kt][3] += gelu_f(d[3] + bias.w);
            }
        }
    }
    #pragma unroll
    for(int kt=0;kt<8;kt++){
        #pragma unroll
        for(int r=0;r<4;r++){
            float s = pacc[kt][r];
            s += __shfl_xor(s, 1);
            s += __shfl_xor(s, 2);
            s += __shfl_xor(s, 4);
            s += __shfl_xor(s, 8);
            if(col == 0) s_red[(kt*16 + quad*4 + r)*5 + wave] = s;
        }
    }
    __syncthreads();
    if(t < 128){
        float s = s_red[t*5+0] + s_red[t*5+1] + s_red[t*5+2] + s_red[t*5+3];
        atomicAdd(&poolq[b*128 + t], s);
    }
}

// head
__global__ __launch_bounds__(1024) void fno_head_k(const float* __restrict__ poolq, const float* __restrict__ W2,
                                                   const float* __restrict__ b2, const float* __restrict__ hw,
                                                   const float* __restrict__ hb, float* __restrict__ out){
    __shared__ float s_pool[16][68];
    int t = threadIdx.x;
    int b = t >> 6, j = t & 63;
    const float* pq = poolq + b*128;
    const float* w2 = W2 + j*128;
    float dot = 0.0f;
    for(int k=0;k<128;k++) dot += w2[k]*pq[k];
    s_pool[b][j] = b2[j] + dot*(1.0f/65536.0f);
    __syncthreads();
    if(t < 32){
        int bb = t >> 1, c2 = t & 1;
        float z = hb[c2];
        #pragma unroll
        for(int j2=0;j2<64;j2++) z += hw[c2*64 + j2]*s_pool[bb][j2];
        out[bb*2 + c2] = tanhf(z);
    }
}

extern "C" void kernel_launch(void* const* d_in, const int* in_sizes, int n_in,
                              void* d_out, int out_size, void* d_ws, size_t ws_size,
                              hipStream_t stream) {
    const float* x       = (const float*)d_in[0];
    const float* lift_w  = (const float*)d_in[1];
    const float* lift_b  = (const float*)d_in[2];
    const float* w1r     = (const float*)d_in[3];
    const float* w1i     = (const float*)d_in[4];
    const float* w2r     = (const float*)d_in[5];
    const float* w2i     = (const float*)d_in[6];
    const float* skip_w  = (const float*)d_in[7];
    const float* skip_b  = (const float*)d_in[8];
    const float* proj_w1 = (const float*)d_in[9];
    const float* proj_b1 = (const float*)d_in[10];
    const float* proj_w2 = (const float*)d_in[11];
    const float* proj_b2 = (const float*)d_in[12];
    const float* head_w  = (const float*)d_in[13];
    const float* head_b  = (const float*)d_in[14];
    float* out = (float*)d_out;

    u32*    vp   = (u32*)d_ws;                   // 16,777,216 u32 (packed hi|lo v)
    float2* Fw   = (float2*)(vp + 16777216);     // 1,048,576 float2
    float2* vftp = Fw  + 1048576;                // 524,288 float2
    float2* Gh   = vftp + 524288;                // 1,048,576 float2
    float2* Wt2  = Gh  + 1048576;                // 524,288 float2
    float*  poolq = (float*)(Wt2 + 524288);      // 2,048 floats
    unsigned short* Ep  = (unsigned short*)(poolq + 2048);   // 16,384 shorts
    unsigned short* Fp  = Ep + 16384;                        // 32,768 shorts
    unsigned short* skA = Fp + 32768;                        // 4,096 shorts
    unsigned short* W1A = skA + 4096;                        // 4,096 shorts

    fno_prep_k<<<2280, 256, 0, stream>>>(w1r, w1i, w2r, w2i, Wt2,
                                         skip_w, proj_w1, Ep, Fp, skA, W1A, poolq);
    fno_liftf1_k<<<4096, 256, 0, stream>>>(x, lift_w, lift_b, vp, Fw);

    for(int l=0; l<4; l++){
        fno_f2q_k<<<1024, 256, 0, stream>>>(Fw, vftp);
        fno_mixi1_k<<<512, 256, 0, stream>>>(vftp, Wt2, Gh, l);
        if(l < 3){
            fno_layer_k<<<1024, 256, 0, stream>>>(Gh, vp, Ep, Fp, skA, skip_b, Fw, l);
        } else {
            fno_l3proj_k<<<1024, 256, 0, stream>>>(Gh, vp, Ep, skA, skip_b, W1A, proj_b1, poolq);
        }
    }

    fno_head_k<<<1, 1024, 0, stream>>>(poolq, proj_w2, proj_b2, head_w, head_b, out);
}

// Round 15
// 390.971 us; speedup vs baseline: 1.1445x; 1.0299x over previous
//
#include <hip/hip_runtime.h>
#include <math.h>

// FNO with global head, MI355X. Round 15: r14 + 2-row groups (grid 2048) for both
// MFMA layer kernels -> 2x oversubscription / better load balance; layer_k LDS
// 49->33 KB (4 resident blocks/CU instead of 3).

#define TWO_PI_OVER_256 0.024543692606170259f

typedef short bf16x8 __attribute__((ext_vector_type(8)));
typedef float f32x4  __attribute__((ext_vector_type(4)));
typedef unsigned int u32;

__device__ __forceinline__ unsigned short bf16_rn(float f){
    unsigned int u = __float_as_uint(f);
    unsigned int r = (u + 0x7fffu + ((u >> 16) & 1u)) >> 16;
    return (unsigned short)r;
}
__device__ __forceinline__ float bf16_tf(unsigned short h){
    return __uint_as_float(((unsigned int)h) << 16);
}
__device__ __forceinline__ u32 pack_hilo(float f){
    unsigned short hi = bf16_rn(f);
    unsigned short lo = bf16_rn(f - bf16_tf(hi));
    return (u32)hi | ((u32)lo << 16);
}

__device__ __forceinline__ float gelu_f(float x){
    float x2 = x*x;
    float z2 = x*(1.5957691f + 0.07135482f*x2);
    float e = __expf(-z2);
    return x * __builtin_amdgcn_rcpf(1.0f + e);
}

__device__ __forceinline__ void build_tables(float* s_c, float* s_s){
    int t = threadIdx.x;
    if(t < 256){
        float ang = (float)t * TWO_PI_OVER_256;
        float sv, cv;
        sincosf(ang, &sv, &cv);
        s_c[t] = cv; s_s[t] = sv;
    }
}

__device__ __forceinline__ float2 dft_row(const float* s_row, const float* s_c, const float* s_s, int ky){
    float stc = s_c[(4*ky)&255], sts = s_s[(4*ky)&255];
    float rc = 1.0f, rs = 0.0f;
    float accR[4] = {0,0,0,0}, accI[4] = {0,0,0,0};
    const float4* row4 = (const float4*)s_row;
    #pragma unroll 4
    for(int m=0;m<64;m++){
        float4 v4 = row4[m];
        accR[0]+=v4.x*rc; accI[0]+=v4.x*rs;
        accR[1]+=v4.y*rc; accI[1]+=v4.y*rs;
        accR[2]+=v4.z*rc; accI[2]+=v4.z*rs;
        accR[3]+=v4.w*rc; accI[3]+=v4.w*rs;
        float nr = rc*stc + rs*sts;
        float ni = rs*stc - rc*sts;
        rc=nr; rs=ni;
    }
    float oR=0.0f, oI=0.0f;
    #pragma unroll
    for(int j=0;j<4;j++){
        float cj = s_c[(ky*j)&255], sj = s_s[(ky*j)&255];
        oR += accR[j]*cj + accI[j]*sj;
        oI += accI[j]*cj - accR[j]*sj;
    }
    return make_float2(oR, oI);
}

// Merged prep: blocks [0,2048) wprep, [2048,2272) tabs, [2272,2280) zero poolq.
__global__ __launch_bounds__(256) void fno_prep_k(const float* __restrict__ w1r, const float* __restrict__ w1i,
                                                  const float* __restrict__ w2r, const float* __restrict__ w2i,
                                                  float2* __restrict__ Wt2,
                                                  const float* __restrict__ skw, const float* __restrict__ W1,
                                                  unsigned short* __restrict__ Ep, unsigned short* __restrict__ Fp,
                                                  unsigned short* __restrict__ skA, unsigned short* __restrict__ W1A,
                                                  float* __restrict__ poolq){
    int blk = blockIdx.x;
    int t = threadIdx.x;
    if(blk < 2048){
        int l  = blk >> 9;
        int rem = blk & 511;
        int o = rem >> 5;
        int kxIdx = rem & 31;
        int ky = t >> 4, i = t & 15;
        int x = kxIdx & 15;
        const float* wr = (kxIdx < 16) ? w1r : w2r;
        const float* wi = (kxIdx < 16) ? w1i : w2i;
        int src = (((l*16 + i)*16 + o)*16 + x)*16 + ky;
        Wt2[((size_t)(l*16 + o)*512 + kxIdx*16 + ky)*16 + i] = make_float2(wr[src], wi[src]);
    } else if(blk < 2272){
        int idx = (blk - 2048)*256 + t;
        if(idx < 16384){
            int rem = idx;
            int pass = rem >> 13; rem &= 8191;
            int nt = rem >> 9; rem &= 511;
            int quad = rem >> 7;
            int col = (rem >> 3) & 15;
            int j = rem & 7;
            int k = quad*8 + j;
            int ky = k >> 1, ri = k & 1;
            int w = nt*16 + col;
            int ph = (ky*w) & 255;
            float sv, cv; sincosf((float)ph * TWO_PI_OVER_256, &sv, &cv);
            float val = ri ? -sv : cv;
            unsigned short hi = bf16_rn(val);
            Ep[idx] = pass ? bf16_rn(val - bf16_tf(hi)) : hi;
        } else if(idx < 16384 + 32768){
            int rem = idx - 16384;
            int pass = rem >> 14; rem &= 16383;
            int nt2 = rem >> 13; rem &= 8191;
            int s = rem >> 9; rem &= 511;
            int quad = rem >> 7;
            int col = (rem >> 3) & 15;
            int j = rem & 7;
            int wp = s*16 + quad*4 + (j >> 1);
            int kyRI = nt2*16 + col;
            int ky = kyRI >> 1, ri = kyRI & 1;
            int ph = (ky*wp) & 255;
            float sv, cv; sincosf((float)ph * TWO_PI_OVER_256, &sv, &cv);
            float val = ri ? -sv : cv;
            unsigned short hi = bf16_rn(val);
            Fp[idx - 16384] = pass ? bf16_rn(val - bf16_tf(hi)) : hi;
        } else if(idx < 16384 + 32768 + 4096){
            int rem = idx - (16384 + 32768);
            int l = rem >> 10;
            int part = (rem >> 9) & 1;
            int quad = (rem >> 7) & 3;
            int col = (rem >> 3) & 15;
            int j = rem & 7;
            int c = quad*4 + (j >> 1);
            float wv = skw[(l*16 + col)*16 + c];
            unsigned short hi = bf16_rn(wv);
            skA[rem] = part ? bf16_rn(wv - bf16_tf(hi)) : hi;
        } else if(idx < 16384 + 32768 + 4096 + 4096){
            int rem = idx - (16384 + 32768 + 4096);
            int kt = rem >> 9;
            int quad = (rem >> 7) & 3;
            int col = (rem >> 3) & 15;
            int j = rem & 7;
            float wv = W1[(kt*16 + col)*16 + (quad & 1)*8 + j];
            unsigned short hi = bf16_rn(wv);
            W1A[rem] = (quad >> 1) ? bf16_rn(wv - bf16_tf(hi)) : hi;
        }
    } else {
        int i = (blk - 2272)*256 + t;
        if(i < 2048) poolq[i] = 0.0f;
    }
}

// lift + row DFT + packed-v store. grid 4096 (b,h).
__global__ __launch_bounds__(256) void fno_liftf1_k(const float* __restrict__ x, const float* __restrict__ lw,
                                                    const float* __restrict__ lb, u32* __restrict__ vp,
                                                    float2* __restrict__ Fw){
    __shared__ float s_v[16*260];
    __shared__ float s_c[256], s_s[256];
    int t = threadIdx.x;
    build_tables(s_c, s_s);
    int b = blockIdx.x >> 8, h = blockIdx.x & 255;
    float xv = x[(b*256 + h)*256 + t];
    #pragma unroll
    for(int c=0;c<16;c++){
        float val = lw[c]*xv + lb[c];
        s_v[c*260 + t] = val;
    }
    __syncthreads();
    uint4* vp4 = (uint4*)(vp + (size_t)(b*256 + h)*4096);
    #pragma unroll
    for(int it=0;it<4;it++){
        int idx = it*256 + t;
        int px = idx >> 2, sg = idx & 3;
        int cg = sg ^ ((px >> 2) & 3);
        uint4 pk;
        pk.x = pack_hilo(s_v[(cg*4+0)*260 + px]);
        pk.y = pack_hilo(s_v[(cg*4+1)*260 + px]);
        pk.z = pack_hilo(s_v[(cg*4+2)*260 + px]);
        pk.w = pack_hilo(s_v[(cg*4+3)*260 + px]);
        vp4[idx] = pk;
    }
    int c = t >> 4, ky = t & 15;
    float2 r = dft_row(s_v + c*260, s_c, s_s, ky);
    Fw[((size_t)(b*16 + c)*256 + h)*16 + ky] = r;
}

// F2 quarter-split (f32). grid 1024.
__global__ __launch_bounds__(256) void fno_f2q_k(const float2* __restrict__ Fw, float2* __restrict__ vftp){
    __shared__ float2 s_fw[1024];
    __shared__ float2 s_red[2048];
    __shared__ float s_c[256], s_s[256];
    int t = threadIdx.x;
    build_tables(s_c, s_s);
    int bc = blockIdx.x >> 2, qr = blockIdx.x & 3;
    int qh = qr*64;
    {
        const float4* src = (const float4*)(Fw + (size_t)bc*4096 + qh*16);
        float4* d4 = (float4*)s_fw;
        for(int i=t;i<512;i+=256) d4[i] = src[i];
    }
    __syncthreads();
    int sub = t>>6, kyp = (t>>3)&7, kxg = t&7;
    int h0 = qh + sub*16;
    float rc[4], rs[4], stc[4], sts[4], aR[4][2], aI[4][2];
    #pragma unroll
    for(int p=0;p<4;p++){
        int kxIdx = kxg*4+p;
        int kx = kxIdx + ((kxIdx>=16)?224:0);
        int i0 = (kx*h0)&255;
        rc[p] = s_c[i0]; rs[p] = -s_s[i0];
        stc[p] = s_c[kx]; sts[p] = s_s[kx];
        aR[p][0]=aR[p][1]=aI[p][0]=aI[p][1]=0.0f;
    }
    #pragma unroll 4
    for(int hh=0; hh<16; hh++){
        float4 f = *(const float4*)&s_fw[(sub*16 + hh)*16 + kyp*2];
        #pragma unroll
        for(int p=0;p<4;p++){
            aR[p][0] += f.x*rc[p] - f.y*rs[p];
            aI[p][0] += f.x*rs[p] + f.y*rc[p];
            aR[p][1] += f.z*rc[p] - f.w*rs[p];
            aI[p][1] += f.z*rs[p] + f.w*rc[p];
            float nr = rc[p]*stc[p] + rs[p]*sts[p];
            float ni = rs[p]*stc[p] - rc[p]*sts[p];
            rc[p]=nr; rs[p]=ni;
        }
    }
    #pragma unroll
    for(int p=0;p<4;p++)
        #pragma unroll
        for(int y=0;y<2;y++)
            s_red[sub*512 + (kxg*4+p)*16 + kyp*2 + y] = make_float2(aR[p][y], aI[p][y]);
    __syncthreads();
    #pragma unroll
    for(int u=0;u<2;u++){
        int oidx = t*2 + u;
        float xr=0.0f, xi=0.0f;
        #pragma unroll
        for(int q=0;q<4;q++){ float2 pr = s_red[q*512 + oidx]; xr += pr.x; xi += pr.y; }
        vftp[(size_t)blockIdx.x*512 + oidx] = make_float2(xr, xi);
    }
}

// mix + I1 fused (f32), ky-half split. grid 512 = (b, o, kyh).
__global__ __launch_bounds__(256) void fno_mixi1_k(const float2* __restrict__ vftp, const float2* __restrict__ Wt2,
                                                   float2* __restrict__ Gh, int l){
    __shared__ float2 s_oft[256];     // [kx 32][kyl 8]
    __shared__ float s_c[256], s_s[256];
    int t = threadIdx.x;
    build_tables(s_c, s_s);
    int b = blockIdx.x >> 5;
    int o = (blockIdx.x >> 1) & 15;
    int kyh = blockIdx.x & 1;
    const float2* vb = vftp + (size_t)b*16*2048;
    const float2* wb = Wt2 + (size_t)(l*16 + o)*512*16;
    {
        int kx = t >> 3, kyl = t & 7;
        int m = kx*16 + kyh*8 + kyl;
        const float2* wm = wb + m*16;
        float aR=0.0f, aI=0.0f;
        #pragma unroll
        for(int i=0;i<16;i++){
            const float2* q0 = vb + i*2048 + m;
            float2 a0 = q0[0], a1 = q0[512], a2 = q0[1024], a3 = q0[1536];
            float vxr = a0.x+a1.x+a2.x+a3.x;
            float vxi = a0.y+a1.y+a2.y+a3.y;
            float2 wv = wm[i];
            aR += vxr*wv.x - vxi*wv.y;
            aI += vxr*wv.y + vxi*wv.x;
        }
        s_oft[t] = make_float2(aR, aI);
    }
    __syncthreads();
    int h = t;
    float hc = s_c[h], hs = s_s[h];
    float aR[8], aI[8];
    #pragma unroll
    for(int q=0;q<8;q++){ aR[q]=0.0f; aI[q]=0.0f; }
    float rc = 1.0f, rs = 0.0f;
    for(int kxIdx=0;kxIdx<16;kxIdx++){
        #pragma unroll
        for(int q=0;q<8;q++){
            float2 g = s_oft[kxIdx*8 + q];
            aR[q] += g.x*rc - g.y*rs;
            aI[q] += g.x*rs + g.y*rc;
        }
        float nr = rc*hc - rs*hs, ni = rc*hs + rs*hc;
        rc=nr; rs=ni;
    }
    { int i0 = (240*h)&255; rc = s_c[i0]; rs = s_s[i0]; }
    for(int kxIdx=16;kxIdx<32;kxIdx++){
        #pragma unroll
        for(int q=0;q<8;q++){
            float2 g = s_oft[kxIdx*8 + q];
            aR[q] += g.x*rc - g.y*rs;
            aI[q] += g.x*rs + g.y*rc;
        }
        float nr = rc*hc - rs*hs, ni = rc*hs + rs*hc;
        rc=nr; rs=ni;
    }
    const float inv = 1.0f/65536.0f;
    float4 pack[4];
    #pragma unroll
    for(int q=0;q<8;q+=2){
        float s0 = (kyh==0 && q==0) ? inv : 2.0f*inv;
        float s1 = 2.0f*inv;
        pack[q/2] = make_float4(aR[q]*s0, aI[q]*s0, aR[q+1]*s1, aI[q+1]*s1);
    }
    float4* d4 = (float4*)(Gh + ((size_t)(b*256 + h)*16 + o)*16 + kyh*8);
    #pragma unroll
    for(int q=0;q<4;q++) d4[q] = pack[q];
}

// G -> A-fragment, hi only.
__device__ __forceinline__ bf16x8 load_G_hi(const float2* __restrict__ Gh, int b, int h,
                                            int quad, int col){
    const float* gp = (const float*)Gh + (size_t)(b*256 + h)*512 + col*32 + quad*8;
    float4 g0 = *(const float4*)gp;
    float4 g1 = *(const float4*)(gp + 4);
    float g[8] = {g0.x,g0.y,g0.z,g0.w,g1.x,g1.y,g1.z,g1.w};
    bf16x8 ghi;
    #pragma unroll
    for(int j=0;j<8;j++) ghi[j] = (short)bf16_rn(g[j]);
    return ghi;
}

// Layer kernel (l<3). grid 2048 = (b, 2-row group), loop 2 h.
__global__ __launch_bounds__(256) void fno_layer_k(const float2* __restrict__ Gh, u32* __restrict__ vp,
                                                   const unsigned short* __restrict__ Ep,
                                                   const unsigned short* __restrict__ Fp,
                                                   const unsigned short* __restrict__ skA,
                                                   const float* __restrict__ skb,
                                                   float2* __restrict__ Fw, int l){
    __shared__ u32 s_hilo[16*260];      // 16.6KB [c][w] packed
    __shared__ float s_part2[2*2048];   // 16KB [hi2][(wave*2+nt2)*64+lane][4]
    int t = threadIdx.x;
    int wave = t >> 6, lane = t & 63, quad = lane >> 4, col = lane & 15;
    int b = blockIdx.x >> 7, hg = blockIdx.x & 127;

    bf16x8 a_whi = *(const bf16x8*)&skA[((l*2 + 0)*64 + lane)*8];
    float4 skb4 = *(const float4*)&skb[l*16 + quad*4];
    float bv[4] = {skb4.x, skb4.y, skb4.z, skb4.w};
    int qs = quad ^ ((col >> 2) & 3);

    for(int hi2=0; hi2<2; hi2++){
        int h = hg*2 + hi2;
        u32* vpb = vp + (size_t)(b*256 + h)*4096;
        bf16x8 ghi = load_G_hi(Gh, b, h, quad, col);
        #pragma unroll
        for(int i=0;i<4;i++){
            int nt = wave*4 + i;
            int w = nt*16 + col;
            bf16x8 bskip = *(const bf16x8*)&vpb[w*16 + qs*4];
            bf16x8 behi = *(const bf16x8*)&Ep[((0*16 + nt)*64 + lane)*8];
            f32x4 acc = {0.0f,0.0f,0.0f,0.0f};
            acc = __builtin_amdgcn_mfma_f32_16x16x32_bf16(a_whi, bskip, acc, 0,0,0);
            acc = __builtin_amdgcn_mfma_f32_16x16x32_bf16(ghi, behi, acc, 0,0,0);
            uint4 pk;
            u32* pkp = (u32*)&pk;
            #pragma unroll
            for(int r=0;r<4;r++){
                float val = gelu_f(acc[r] + bv[r]);
                int o = quad*4 + r;
                u32 p = pack_hilo(val);
                s_hilo[o*260 + w] = p;
                pkp[r] = p;
            }
            *(uint4*)&vpb[w*16 + qs*4] = pk;
        }
        // wave-local s_hilo tile: no barrier (r11/r12-validated)
        f32x4 facc[2];
        facc[0] = (f32x4){0,0,0,0}; facc[1] = (f32x4){0,0,0,0};
        #pragma unroll
        for(int si=0;si<4;si++){
            int s = wave*4 + si;
            bf16x8 af = *(const bf16x8*)&s_hilo[col*260 + s*16 + quad*4];
            #pragma unroll
            for(int nt2=0;nt2<2;nt2++){
                bf16x8 bhi = *(const bf16x8*)&Fp[(((0*2 + nt2)*16 + s)*64 + lane)*8];
                facc[nt2] = __builtin_amdgcn_mfma_f32_16x16x32_bf16(af, bhi, facc[nt2], 0,0,0);
            }
        }
        #pragma unroll
        for(int nt2=0;nt2<2;nt2++){
            float4 fv = {facc[nt2][0], facc[nt2][1], facc[nt2][2], facc[nt2][3]};
            *(float4*)&s_part2[hi2*2048 + ((wave*2 + nt2)*64 + lane)*4] = fv;
        }
    }
    __syncthreads();    // the only block-wide barrier
    {
        int c = t >> 4, jj = t & 15;
        int nt2 = jj >> 3, kyl = jj & 7;
        int ky = nt2*8 + kyl;
        int lidx = (c >> 2)*16 + kyl*2;
        int reg = c & 3;
        #pragma unroll
        for(int hi2=0;hi2<2;hi2++){
            float re = 0.0f, im = 0.0f;
            #pragma unroll
            for(int wv=0;wv<4;wv++){
                re += s_part2[hi2*2048 + ((wv*2 + nt2)*64 + lidx)*4 + reg];
                im += s_part2[hi2*2048 + ((wv*2 + nt2)*64 + lidx + 1)*4 + reg];
            }
            Fw[((size_t)(b*16 + c)*256 + hg*2 + hi2)*16 + ky] = make_float2(re, im);
        }
    }
}

// Layer-3 + projection fused. grid 2048 = (b, 2-row group), loop 2 h.
__global__ __launch_bounds__(256) void fno_l3proj_k(const float2* __restrict__ Gh, const u32* __restrict__ vp,
                                                    const unsigned short* __restrict__ Ep,
                                                    const unsigned short* __restrict__ skA,
                                                    const float* __restrict__ skb,
                                                    const unsigned short* __restrict__ W1A,
                                                    const float* __restrict__ b1,
                                                    float* __restrict__ poolq){
    __shared__ unsigned short s_b2[4096];   // 8KB v_new bf16 [px][c], wave-local tiles
    __shared__ float s_b1[128];
    __shared__ float s_red[128*5];
    int t = threadIdx.x;
    int wave = t >> 6, lane = t & 63, quad = lane >> 4, col = lane & 15;
    int b = blockIdx.x >> 7, hg = blockIdx.x & 127;

    if(t < 128) s_b1[t] = b1[t];
    bf16x8 a_whi = *(const bf16x8*)&skA[((3*2 + 0)*64 + lane)*8];
    float4 skb4 = *(const float4*)&skb[3*16 + quad*4];
    float bv[4] = {skb4.x, skb4.y, skb4.z, skb4.w};
    int qs = quad ^ ((col >> 2) & 3);
    __syncthreads();                       // s_b1 ready; no more barriers until reduce

    float pacc[8][4];
    #pragma unroll
    for(int kt=0;kt<8;kt++)
        #pragma unroll
        for(int r=0;r<4;r++) pacc[kt][r] = 0.0f;

    for(int hi2=0; hi2<2; hi2++){
        int h = hg*2 + hi2;
        const u32* vpb = vp + (size_t)(b*256 + h)*4096;
        bf16x8 ghi = load_G_hi(Gh, b, h, quad, col);
        #pragma unroll
        for(int i=0;i<4;i++){
            int nt = wave*4 + i;
            int w = nt*16 + col;
            bf16x8 bskip = *(const bf16x8*)&vpb[w*16 + qs*4];
            bf16x8 behi = *(const bf16x8*)&Ep[((0*16 + nt)*64 + lane)*8];
            f32x4 acc = {0.0f,0.0f,0.0f,0.0f};
            acc = __builtin_amdgcn_mfma_f32_16x16x32_bf16(a_whi, bskip, acc, 0,0,0);
            acc = __builtin_amdgcn_mfma_f32_16x16x32_bf16(ghi, behi, acc, 0,0,0);
            #pragma unroll
            for(int r=0;r<2;r++){
                u32 p = (u32)bf16_rn(acc[2*r] + bv[2*r]) | ((u32)bf16_rn(acc[2*r+1] + bv[2*r+1]) << 16);
                *(u32*)&s_b2[w*16 + quad*4 + 2*r] = p;
            }
        }
        // wave-local: no __syncthreads
        bf16x8 bfrag[4];
        #pragma unroll
        for(int i=0;i<4;i++){
            int wt = wave*4 + i;
            bfrag[i] = *(const bf16x8*)&s_b2[(wt*16 + col)*16 + (quad & 1)*8];
        }
        #pragma unroll
        for(int kt=0;kt<8;kt++){
            bf16x8 w1 = *(const bf16x8*)&W1A[(kt*64 + lane)*8];
            float4 bias = *(const float4*)&s_b1[kt*16 + quad*4];
            #pragma unroll
            for(int i=0;i<4;i++){
                f32x4 d = {0.0f,0.0f,0.0f,0.0f};
                d = __builtin_amdgcn_mfma_f32_16x16x32_bf16(w1, bfrag[i], d, 0,0,0);
                pacc[kt][0] += gelu_f(d[0] + bias.x);
                pacc[kt][1] += gelu_f(d[1] + bias.y);
                pacc[kt][2] += gelu_f(d[2] + bias.z);
                pacc[kt][3] += gelu_f(d[3] + bias.w);
            }
        }
    }
    #pragma unroll
    for(int kt=0;kt<8;kt++){
        #pragma unroll
        for(int r=0;r<4;r++){
            float s = pacc[kt][r];
            s += __shfl_xor(s, 1);
            s += __shfl_xor(s, 2);
            s += __shfl_xor(s, 4);
            s += __shfl_xor(s, 8);
            if(col == 0) s_red[(kt*16 + quad*4 + r)*5 + wave] = s;
        }
    }
    __syncthreads();
    if(t < 128){
        float s = s_red[t*5+0] + s_red[t*5+1] + s_red[t*5+2] + s_red[t*5+3];
        atomicAdd(&poolq[b*128 + t], s);
    }
}

// head
__global__ __launch_bounds__(1024) void fno_head_k(const float* __restrict__ poolq, const float* __restrict__ W2,
                                                   const float* __restrict__ b2, const float* __restrict__ hw,
                                                   const float* __restrict__ hb, float* __restrict__ out){
    __shared__ float s_pool[16][68];
    int t = threadIdx.x;
    int b = t >> 6, j = t & 63;
    const float* pq = poolq + b*128;
    const float* w2 = W2 + j*128;
    float dot = 0.0f;
    for(int k=0;k<128;k++) dot += w2[k]*pq[k];
    s_pool[b][j] = b2[j] + dot*(1.0f/65536.0f);
    __syncthreads();
    if(t < 32){
        int bb = t >> 1, c2 = t & 1;
        float z = hb[c2];
        #pragma unroll
        for(int j2=0;j2<64;j2++) z += hw[c2*64 + j2]*s_pool[bb][j2];
        out[bb*2 + c2] = tanhf(z);
    }
}

extern "C" void kernel_launch(void* const* d_in, const int* in_sizes, int n_in,
                              void* d_out, int out_size, void* d_ws, size_t ws_size,
                              hipStream_t stream) {
    const float* x       = (const float*)d_in[0];
    const float* lift_w  = (const float*)d_in[1];
    const float* lift_b  = (const float*)d_in[2];
    const float* w1r     = (const float*)d_in[3];
    const float* w1i     = (const float*)d_in[4];
    const float* w2r     = (const float*)d_in[5];
    const float* w2i     = (const float*)d_in[6];
    const float* skip_w  = (const float*)d_in[7];
    const float* skip_b  = (const float*)d_in[8];
    const float* proj_w1 = (const float*)d_in[9];
    const float* proj_b1 = (const float*)d_in[10];
    const float* proj_w2 = (const float*)d_in[11];
    const float* proj_b2 = (const float*)d_in[12];
    const float* head_w  = (const float*)d_in[13];
    const float* head_b  = (const float*)d_in[14];
    float* out = (float*)d_out;

    u32*    vp   = (u32*)d_ws;                   // 16,777,216 u32 (packed hi|lo v)
    float2* Fw   = (float2*)(vp + 16777216);     // 1,048,576 float2
    float2* vftp = Fw  + 1048576;                // 524,288 float2
    float2* Gh   = vftp + 524288;                // 1,048,576 float2
    float2* Wt2  = Gh  + 1048576;                // 524,288 float2
    float*  poolq = (float*)(Wt2 + 524288);      // 2,048 floats
    unsigned short* Ep  = (unsigned short*)(poolq + 2048);   // 16,384 shorts
    unsigned short* Fp  = Ep + 16384;                        // 32,768 shorts
    unsigned short* skA = Fp + 32768;                        // 4,096 shorts
    unsigned short* W1A = skA + 4096;                        // 4,096 shorts

    fno_prep_k<<<2280, 256, 0, stream>>>(w1r, w1i, w2r, w2i, Wt2,
                                         skip_w, proj_w1, Ep, Fp, skA, W1A, poolq);
    fno_liftf1_k<<<4096, 256, 0, stream>>>(x, lift_w, lift_b, vp, Fw);

    for(int l=0; l<4; l++){
        fno_f2q_k<<<1024, 256, 0, stream>>>(Fw, vftp);
        fno_mixi1_k<<<512, 256, 0, stream>>>(vftp, Wt2, Gh, l);
        if(l < 3){
            fno_layer_k<<<2048, 256, 0, stream>>>(Gh, vp, Ep, Fp, skA, skip_b, Fw, l);
        } else {
            fno_l3proj_k<<<2048, 256, 0, stream>>>(Gh, vp, Ep, skA, skip_b, W1A, proj_b1, poolq);
        }
    }

    fno_head_k<<<1, 1024, 0, stream>>>(poolq, proj_w2, proj_b2, head_w, head_b, out);
}

// Round 16
// 379.235 us; speedup vs baseline: 1.1799x; 1.0309x over previous
//
#include <hip/hip_runtime.h>
#include <math.h>

// FNO with global head, MI355X. Round 16: hybrid of measured optima —
// layer_k at 2-row groups (r15 win), l3proj at 4-row groups (r14 optimum;
// r15's 2-row split regressed it 69.5->81.3 via per-block reduction overhead).

#define TWO_PI_OVER_256 0.024543692606170259f

typedef short bf16x8 __attribute__((ext_vector_type(8)));
typedef float f32x4  __attribute__((ext_vector_type(4)));
typedef unsigned int u32;

__device__ __forceinline__ unsigned short bf16_rn(float f){
    unsigned int u = __float_as_uint(f);
    unsigned int r = (u + 0x7fffu + ((u >> 16) & 1u)) >> 16;
    return (unsigned short)r;
}
__device__ __forceinline__ float bf16_tf(unsigned short h){
    return __uint_as_float(((unsigned int)h) << 16);
}
__device__ __forceinline__ u32 pack_hilo(float f){
    unsigned short hi = bf16_rn(f);
    unsigned short lo = bf16_rn(f - bf16_tf(hi));
    return (u32)hi | ((u32)lo << 16);
}

__device__ __forceinline__ float gelu_f(float x){
    float x2 = x*x;
    float z2 = x*(1.5957691f + 0.07135482f*x2);
    float e = __expf(-z2);
    return x * __builtin_amdgcn_rcpf(1.0f + e);
}

__device__ __forceinline__ void build_tables(float* s_c, float* s_s){
    int t = threadIdx.x;
    if(t < 256){
        float ang = (float)t * TWO_PI_OVER_256;
        float sv, cv;
        sincosf(ang, &sv, &cv);
        s_c[t] = cv; s_s[t] = sv;
    }
}

__device__ __forceinline__ float2 dft_row(const float* s_row, const float* s_c, const float* s_s, int ky){
    float stc = s_c[(4*ky)&255], sts = s_s[(4*ky)&255];
    float rc = 1.0f, rs = 0.0f;
    float accR[4] = {0,0,0,0}, accI[4] = {0,0,0,0};
    const float4* row4 = (const float4*)s_row;
    #pragma unroll 4
    for(int m=0;m<64;m++){
        float4 v4 = row4[m];
        accR[0]+=v4.x*rc; accI[0]+=v4.x*rs;
        accR[1]+=v4.y*rc; accI[1]+=v4.y*rs;
        accR[2]+=v4.z*rc; accI[2]+=v4.z*rs;
        accR[3]+=v4.w*rc; accI[3]+=v4.w*rs;
        float nr = rc*stc + rs*sts;
        float ni = rs*stc - rc*sts;
        rc=nr; rs=ni;
    }
    float oR=0.0f, oI=0.0f;
    #pragma unroll
    for(int j=0;j<4;j++){
        float cj = s_c[(ky*j)&255], sj = s_s[(ky*j)&255];
        oR += accR[j]*cj + accI[j]*sj;
        oI += accI[j]*cj - accR[j]*sj;
    }
    return make_float2(oR, oI);
}

// Merged prep: blocks [0,2048) wprep, [2048,2272) tabs, [2272,2280) zero poolq.
__global__ __launch_bounds__(256) void fno_prep_k(const float* __restrict__ w1r, const float* __restrict__ w1i,
                                                  const float* __restrict__ w2r, const float* __restrict__ w2i,
                                                  float2* __restrict__ Wt2,
                                                  const float* __restrict__ skw, const float* __restrict__ W1,
                                                  unsigned short* __restrict__ Ep, unsigned short* __restrict__ Fp,
                                                  unsigned short* __restrict__ skA, unsigned short* __restrict__ W1A,
                                                  float* __restrict__ poolq){
    int blk = blockIdx.x;
    int t = threadIdx.x;
    if(blk < 2048){
        int l  = blk >> 9;
        int rem = blk & 511;
        int o = rem >> 5;
        int kxIdx = rem & 31;
        int ky = t >> 4, i = t & 15;
        int x = kxIdx & 15;
        const float* wr = (kxIdx < 16) ? w1r : w2r;
        const float* wi = (kxIdx < 16) ? w1i : w2i;
        int src = (((l*16 + i)*16 + o)*16 + x)*16 + ky;
        Wt2[((size_t)(l*16 + o)*512 + kxIdx*16 + ky)*16 + i] = make_float2(wr[src], wi[src]);
    } else if(blk < 2272){
        int idx = (blk - 2048)*256 + t;
        if(idx < 16384){
            int rem = idx;
            int pass = rem >> 13; rem &= 8191;
            int nt = rem >> 9; rem &= 511;
            int quad = rem >> 7;
            int col = (rem >> 3) & 15;
            int j = rem & 7;
            int k = quad*8 + j;
            int ky = k >> 1, ri = k & 1;
            int w = nt*16 + col;
            int ph = (ky*w) & 255;
            float sv, cv; sincosf((float)ph * TWO_PI_OVER_256, &sv, &cv);
            float val = ri ? -sv : cv;
            unsigned short hi = bf16_rn(val);
            Ep[idx] = pass ? bf16_rn(val - bf16_tf(hi)) : hi;
        } else if(idx < 16384 + 32768){
            int rem = idx - 16384;
            int pass = rem >> 14; rem &= 16383;
            int nt2 = rem >> 13; rem &= 8191;
            int s = rem >> 9; rem &= 511;
            int quad = rem >> 7;
            int col = (rem >> 3) & 15;
            int j = rem & 7;
            int wp = s*16 + quad*4 + (j >> 1);
            int kyRI = nt2*16 + col;
            int ky = kyRI >> 1, ri = kyRI & 1;
            int ph = (ky*wp) & 255;
            float sv, cv; sincosf((float)ph * TWO_PI_OVER_256, &sv, &cv);
            float val = ri ? -sv : cv;
            unsigned short hi = bf16_rn(val);
            Fp[idx - 16384] = pass ? bf16_rn(val - bf16_tf(hi)) : hi;
        } else if(idx < 16384 + 32768 + 4096){
            int rem = idx - (16384 + 32768);
            int l = rem >> 10;
            int part = (rem >> 9) & 1;
            int quad = (rem >> 7) & 3;
            int col = (rem >> 3) & 15;
            int j = rem & 7;
            int c = quad*4 + (j >> 1);
            float wv = skw[(l*16 + col)*16 + c];
            unsigned short hi = bf16_rn(wv);
            skA[rem] = part ? bf16_rn(wv - bf16_tf(hi)) : hi;
        } else if(idx < 16384 + 32768 + 4096 + 4096){
            int rem = idx - (16384 + 32768 + 4096);
            int kt = rem >> 9;
            int quad = (rem >> 7) & 3;
            int col = (rem >> 3) & 15;
            int j = rem & 7;
            float wv = W1[(kt*16 + col)*16 + (quad & 1)*8 + j];
            unsigned short hi = bf16_rn(wv);
            W1A[rem] = (quad >> 1) ? bf16_rn(wv - bf16_tf(hi)) : hi;
        }
    } else {
        int i = (blk - 2272)*256 + t;
        if(i < 2048) poolq[i] = 0.0f;
    }
}

// lift + row DFT + packed-v store. grid 4096 (b,h).
__global__ __launch_bounds__(256) void fno_liftf1_k(const float* __restrict__ x, const float* __restrict__ lw,
                                                    const float* __restrict__ lb, u32* __restrict__ vp,
                                                    float2* __restrict__ Fw){
    __shared__ float s_v[16*260];
    __shared__ float s_c[256], s_s[256];
    int t = threadIdx.x;
    build_tables(s_c, s_s);
    int b = blockIdx.x >> 8, h = blockIdx.x & 255;
    float xv = x[(b*256 + h)*256 + t];
    #pragma unroll
    for(int c=0;c<16;c++){
        float val = lw[c]*xv + lb[c];
        s_v[c*260 + t] = val;
    }
    __syncthreads();
    uint4* vp4 = (uint4*)(vp + (size_t)(b*256 + h)*4096);
    #pragma unroll
    for(int it=0;it<4;it++){
        int idx = it*256 + t;
        int px = idx >> 2, sg = idx & 3;
        int cg = sg ^ ((px >> 2) & 3);
        uint4 pk;
        pk.x = pack_hilo(s_v[(cg*4+0)*260 + px]);
        pk.y = pack_hilo(s_v[(cg*4+1)*260 + px]);
        pk.z = pack_hilo(s_v[(cg*4+2)*260 + px]);
        pk.w = pack_hilo(s_v[(cg*4+3)*260 + px]);
        vp4[idx] = pk;
    }
    int c = t >> 4, ky = t & 15;
    float2 r = dft_row(s_v + c*260, s_c, s_s, ky);
    Fw[((size_t)(b*16 + c)*256 + h)*16 + ky] = r;
}

// F2 quarter-split (f32). grid 1024.
__global__ __launch_bounds__(256) void fno_f2q_k(const float2* __restrict__ Fw, float2* __restrict__ vftp){
    __shared__ float2 s_fw[1024];
    __shared__ float2 s_red[2048];
    __shared__ float s_c[256], s_s[256];
    int t = threadIdx.x;
    build_tables(s_c, s_s);
    int bc = blockIdx.x >> 2, qr = blockIdx.x & 3;
    int qh = qr*64;
    {
        const float4* src = (const float4*)(Fw + (size_t)bc*4096 + qh*16);
        float4* d4 = (float4*)s_fw;
        for(int i=t;i<512;i+=256) d4[i] = src[i];
    }
    __syncthreads();
    int sub = t>>6, kyp = (t>>3)&7, kxg = t&7;
    int h0 = qh + sub*16;
    float rc[4], rs[4], stc[4], sts[4], aR[4][2], aI[4][2];
    #pragma unroll
    for(int p=0;p<4;p++){
        int kxIdx = kxg*4+p;
        int kx = kxIdx + ((kxIdx>=16)?224:0);
        int i0 = (kx*h0)&255;
        rc[p] = s_c[i0]; rs[p] = -s_s[i0];
        stc[p] = s_c[kx]; sts[p] = s_s[kx];
        aR[p][0]=aR[p][1]=aI[p][0]=aI[p][1]=0.0f;
    }
    #pragma unroll 4
    for(int hh=0; hh<16; hh++){
        float4 f = *(const float4*)&s_fw[(sub*16 + hh)*16 + kyp*2];
        #pragma unroll
        for(int p=0;p<4;p++){
            aR[p][0] += f.x*rc[p] - f.y*rs[p];
            aI[p][0] += f.x*rs[p] + f.y*rc[p];
            aR[p][1] += f.z*rc[p] - f.w*rs[p];
            aI[p][1] += f.z*rs[p] + f.w*rc[p];
            float nr = rc[p]*stc[p] + rs[p]*sts[p];
            float ni = rs[p]*stc[p] - rc[p]*sts[p];
            rc[p]=nr; rs[p]=ni;
        }
    }
    #pragma unroll
    for(int p=0;p<4;p++)
        #pragma unroll
        for(int y=0;y<2;y++)
            s_red[sub*512 + (kxg*4+p)*16 + kyp*2 + y] = make_float2(aR[p][y], aI[p][y]);
    __syncthreads();
    #pragma unroll
    for(int u=0;u<2;u++){
        int oidx = t*2 + u;
        float xr=0.0f, xi=0.0f;
        #pragma unroll
        for(int q=0;q<4;q++){ float2 pr = s_red[q*512 + oidx]; xr += pr.x; xi += pr.y; }
        vftp[(size_t)blockIdx.x*512 + oidx] = make_float2(xr, xi);
    }
}

// mix + I1 fused (f32), ky-half split. grid 512 = (b, o, kyh).
__global__ __launch_bounds__(256) void fno_mixi1_k(const float2* __restrict__ vftp, const float2* __restrict__ Wt2,
                                                   float2* __restrict__ Gh, int l){
    __shared__ float2 s_oft[256];     // [kx 32][kyl 8]
    __shared__ float s_c[256], s_s[256];
    int t = threadIdx.x;
    build_tables(s_c, s_s);
    int b = blockIdx.x >> 5;
    int o = (blockIdx.x >> 1) & 15;
    int kyh = blockIdx.x & 1;
    const float2* vb = vftp + (size_t)b*16*2048;
    const float2* wb = Wt2 + (size_t)(l*16 + o)*512*16;
    {
        int kx = t >> 3, kyl = t & 7;
        int m = kx*16 + kyh*8 + kyl;
        const float2* wm = wb + m*16;
        float aR=0.0f, aI=0.0f;
        #pragma unroll
        for(int i=0;i<16;i++){
            const float2* q0 = vb + i*2048 + m;
            float2 a0 = q0[0], a1 = q0[512], a2 = q0[1024], a3 = q0[1536];
            float vxr = a0.x+a1.x+a2.x+a3.x;
            float vxi = a0.y+a1.y+a2.y+a3.y;
            float2 wv = wm[i];
            aR += vxr*wv.x - vxi*wv.y;
            aI += vxr*wv.y + vxi*wv.x;
        }
        s_oft[t] = make_float2(aR, aI);
    }
    __syncthreads();
    int h = t;
    float hc = s_c[h], hs = s_s[h];
    float aR[8], aI[8];
    #pragma unroll
    for(int q=0;q<8;q++){ aR[q]=0.0f; aI[q]=0.0f; }
    float rc = 1.0f, rs = 0.0f;
    for(int kxIdx=0;kxIdx<16;kxIdx++){
        #pragma unroll
        for(int q=0;q<8;q++){
            float2 g = s_oft[kxIdx*8 + q];
            aR[q] += g.x*rc - g.y*rs;
            aI[q] += g.x*rs + g.y*rc;
        }
        float nr = rc*hc - rs*hs, ni = rc*hs + rs*hc;
        rc=nr; rs=ni;
    }
    { int i0 = (240*h)&255; rc = s_c[i0]; rs = s_s[i0]; }
    for(int kxIdx=16;kxIdx<32;kxIdx++){
        #pragma unroll
        for(int q=0;q<8;q++){
            float2 g = s_oft[kxIdx*8 + q];
            aR[q] += g.x*rc - g.y*rs;
            aI[q] += g.x*rs + g.y*rc;
        }
        float nr = rc*hc - rs*hs, ni = rc*hs + rs*hc;
        rc=nr; rs=ni;
    }
    const float inv = 1.0f/65536.0f;
    float4 pack[4];
    #pragma unroll
    for(int q=0;q<8;q+=2){
        float s0 = (kyh==0 && q==0) ? inv : 2.0f*inv;
        float s1 = 2.0f*inv;
        pack[q/2] = make_float4(aR[q]*s0, aI[q]*s0, aR[q+1]*s1, aI[q+1]*s1);
    }
    float4* d4 = (float4*)(Gh + ((size_t)(b*256 + h)*16 + o)*16 + kyh*8);
    #pragma unroll
    for(int q=0;q<4;q++) d4[q] = pack[q];
}

// G -> A-fragment, hi only.
__device__ __forceinline__ bf16x8 load_G_hi(const float2* __restrict__ Gh, int b, int h,
                                            int quad, int col){
    const float* gp = (const float*)Gh + (size_t)(b*256 + h)*512 + col*32 + quad*8;
    float4 g0 = *(const float4*)gp;
    float4 g1 = *(const float4*)(gp + 4);
    float g[8] = {g0.x,g0.y,g0.z,g0.w,g1.x,g1.y,g1.z,g1.w};
    bf16x8 ghi;
    #pragma unroll
    for(int j=0;j<8;j++) ghi[j] = (short)bf16_rn(g[j]);
    return ghi;
}

// Layer kernel (l<3). grid 2048 = (b, 2-row group), loop 2 h. (r15 win)
__global__ __launch_bounds__(256) void fno_layer_k(const float2* __restrict__ Gh, u32* __restrict__ vp,
                                                   const unsigned short* __restrict__ Ep,
                                                   const unsigned short* __restrict__ Fp,
                                                   const unsigned short* __restrict__ skA,
                                                   const float* __restrict__ skb,
                                                   float2* __restrict__ Fw, int l){
    __shared__ u32 s_hilo[16*260];      // 16.6KB [c][w] packed
    __shared__ float s_part2[2*2048];   // 16KB
    int t = threadIdx.x;
    int wave = t >> 6, lane = t & 63, quad = lane >> 4, col = lane & 15;
    int b = blockIdx.x >> 7, hg = blockIdx.x & 127;

    bf16x8 a_whi = *(const bf16x8*)&skA[((l*2 + 0)*64 + lane)*8];
    float4 skb4 = *(const float4*)&skb[l*16 + quad*4];
    float bv[4] = {skb4.x, skb4.y, skb4.z, skb4.w};
    int qs = quad ^ ((col >> 2) & 3);

    for(int hi2=0; hi2<2; hi2++){
        int h = hg*2 + hi2;
        u32* vpb = vp + (size_t)(b*256 + h)*4096;
        bf16x8 ghi = load_G_hi(Gh, b, h, quad, col);
        #pragma unroll
        for(int i=0;i<4;i++){
            int nt = wave*4 + i;
            int w = nt*16 + col;
            bf16x8 bskip = *(const bf16x8*)&vpb[w*16 + qs*4];
            bf16x8 behi = *(const bf16x8*)&Ep[((0*16 + nt)*64 + lane)*8];
            f32x4 acc = {0.0f,0.0f,0.0f,0.0f};
            acc = __builtin_amdgcn_mfma_f32_16x16x32_bf16(a_whi, bskip, acc, 0,0,0);
            acc = __builtin_amdgcn_mfma_f32_16x16x32_bf16(ghi, behi, acc, 0,0,0);
            uint4 pk;
            u32* pkp = (u32*)&pk;
            #pragma unroll
            for(int r=0;r<4;r++){
                float val = gelu_f(acc[r] + bv[r]);
                int o = quad*4 + r;
                u32 p = pack_hilo(val);
                s_hilo[o*260 + w] = p;
                pkp[r] = p;
            }
            *(uint4*)&vpb[w*16 + qs*4] = pk;
        }
        // wave-local s_hilo tile: no barrier (r11/r12-validated)
        f32x4 facc[2];
        facc[0] = (f32x4){0,0,0,0}; facc[1] = (f32x4){0,0,0,0};
        #pragma unroll
        for(int si=0;si<4;si++){
            int s = wave*4 + si;
            bf16x8 af = *(const bf16x8*)&s_hilo[col*260 + s*16 + quad*4];
            #pragma unroll
            for(int nt2=0;nt2<2;nt2++){
                bf16x8 bhi = *(const bf16x8*)&Fp[(((0*2 + nt2)*16 + s)*64 + lane)*8];
                facc[nt2] = __builtin_amdgcn_mfma_f32_16x16x32_bf16(af, bhi, facc[nt2], 0,0,0);
            }
        }
        #pragma unroll
        for(int nt2=0;nt2<2;nt2++){
            float4 fv = {facc[nt2][0], facc[nt2][1], facc[nt2][2], facc[nt2][3]};
            *(float4*)&s_part2[hi2*2048 + ((wave*2 + nt2)*64 + lane)*4] = fv;
        }
    }
    __syncthreads();    // the only block-wide barrier
    {
        int c = t >> 4, jj = t & 15;
        int nt2 = jj >> 3, kyl = jj & 7;
        int ky = nt2*8 + kyl;
        int lidx = (c >> 2)*16 + kyl*2;
        int reg = c & 3;
        #pragma unroll
        for(int hi2=0;hi2<2;hi2++){
            float re = 0.0f, im = 0.0f;
            #pragma unroll
            for(int wv=0;wv<4;wv++){
                re += s_part2[hi2*2048 + ((wv*2 + nt2)*64 + lidx)*4 + reg];
                im += s_part2[hi2*2048 + ((wv*2 + nt2)*64 + lidx + 1)*4 + reg];
            }
            Fw[((size_t)(b*16 + c)*256 + hg*2 + hi2)*16 + ky] = make_float2(re, im);
        }
    }
}

// Layer-3 + projection fused. grid 1024 = (b, 4-row group), loop 4 h. (r14 optimum)
__global__ __launch_bounds__(256) void fno_l3proj_k(const float2* __restrict__ Gh, const u32* __restrict__ vp,
                                                    const unsigned short* __restrict__ Ep,
                                                    const unsigned short* __restrict__ skA,
                                                    const float* __restrict__ skb,
                                                    const unsigned short* __restrict__ W1A,
                                                    const float* __restrict__ b1,
                                                    float* __restrict__ poolq){
    __shared__ unsigned short s_b2[4096];   // 8KB v_new bf16 [px][c], wave-local tiles
    __shared__ float s_b1[128];
    __shared__ float s_red[128*5];
    int t = threadIdx.x;
    int wave = t >> 6, lane = t & 63, quad = lane >> 4, col = lane & 15;
    int b = blockIdx.x >> 6, hg = blockIdx.x & 63;

    if(t < 128) s_b1[t] = b1[t];
    bf16x8 a_whi = *(const bf16x8*)&skA[((3*2 + 0)*64 + lane)*8];
    float4 skb4 = *(const float4*)&skb[3*16 + quad*4];
    float bv[4] = {skb4.x, skb4.y, skb4.z, skb4.w};
    int qs = quad ^ ((col >> 2) & 3);
    __syncthreads();                       // s_b1 ready; no more barriers until reduce

    float pacc[8][4];
    #pragma unroll
    for(int kt=0;kt<8;kt++)
        #pragma unroll
        for(int r=0;r<4;r++) pacc[kt][r] = 0.0f;

    for(int hi2=0; hi2<4; hi2++){
        int h = hg*4 + hi2;
        const u32* vpb = vp + (size_t)(b*256 + h)*4096;
        bf16x8 ghi = load_G_hi(Gh, b, h, quad, col);
        #pragma unroll
        for(int i=0;i<4;i++){
            int nt = wave*4 + i;
            int w = nt*16 + col;
            bf16x8 bskip = *(const bf16x8*)&vpb[w*16 + qs*4];
            bf16x8 behi = *(const bf16x8*)&Ep[((0*16 + nt)*64 + lane)*8];
            f32x4 acc = {0.0f,0.0f,0.0f,0.0f};
            acc = __builtin_amdgcn_mfma_f32_16x16x32_bf16(a_whi, bskip, acc, 0,0,0);
            acc = __builtin_amdgcn_mfma_f32_16x16x32_bf16(ghi, behi, acc, 0,0,0);
            #pragma unroll
            for(int r=0;r<2;r++){
                u32 p = (u32)bf16_rn(acc[2*r] + bv[2*r]) | ((u32)bf16_rn(acc[2*r+1] + bv[2*r+1]) << 16);
                *(u32*)&s_b2[w*16 + quad*4 + 2*r] = p;
            }
        }
        // wave-local: no __syncthreads
        bf16x8 bfrag[4];
        #pragma unroll
        for(int i=0;i<4;i++){
            int wt = wave*4 + i;
            bfrag[i] = *(const bf16x8*)&s_b2[(wt*16 + col)*16 + (quad & 1)*8];
        }
        #pragma unroll
        for(int kt=0;kt<8;kt++){
            bf16x8 w1 = *(const bf16x8*)&W1A[(kt*64 + lane)*8];
            float4 bias = *(const float4*)&s_b1[kt*16 + quad*4];
            #pragma unroll
            for(int i=0;i<4;i++){
                f32x4 d = {0.0f,0.0f,0.0f,0.0f};
                d = __builtin_amdgcn_mfma_f32_16x16x32_bf16(w1, bfrag[i], d, 0,0,0);
                pacc[kt][0] += gelu_f(d[0] + bias.x);
                pacc[kt][1] += gelu_f(d[1] + bias.y);
                pacc[kt][2] += gelu_f(d[2] + bias.z);
                pacc[kt][3] += gelu_f(d[3] + bias.w);
            }
        }
    }
    #pragma unroll
    for(int kt=0;kt<8;kt++){
        #pragma unroll
        for(int r=0;r<4;r++){
            float s = pacc[kt][r];
            s += __shfl_xor(s, 1);
            s += __shfl_xor(s, 2);
            s += __shfl_xor(s, 4);
            s += __shfl_xor(s, 8);
            if(col == 0) s_red[(kt*16 + quad*4 + r)*5 + wave] = s;
        }
    }
    __syncthreads();
    if(t < 128){
        float s = s_red[t*5+0] + s_red[t*5+1] + s_red[t*5+2] + s_red[t*5+3];
        atomicAdd(&poolq[b*128 + t], s);
    }
}

// head
__global__ __launch_bounds__(1024) void fno_head_k(const float* __restrict__ poolq, const float* __restrict__ W2,
                                                   const float* __restrict__ b2, const float* __restrict__ hw,
                                                   const float* __restrict__ hb, float* __restrict__ out){
    __shared__ float s_pool[16][68];
    int t = threadIdx.x;
    int b = t >> 6, j = t & 63;
    const float* pq = poolq + b*128;
    const float* w2 = W2 + j*128;
    float dot = 0.0f;
    for(int k=0;k<128;k++) dot += w2[k]*pq[k];
    s_pool[b][j] = b2[j] + dot*(1.0f/65536.0f);
    __syncthreads();
    if(t < 32){
        int bb = t >> 1, c2 = t & 1;
        float z = hb[c2];
        #pragma unroll
        for(int j2=0;j2<64;j2++) z += hw[c2*64 + j2]*s_pool[bb][j2];
        out[bb*2 + c2] = tanhf(z);
    }
}

extern "C" void kernel_launch(void* const* d_in, const int* in_sizes, int n_in,
                              void* d_out, int out_size, void* d_ws, size_t ws_size,
                              hipStream_t stream) {
    const float* x       = (const float*)d_in[0];
    const float* lift_w  = (const float*)d_in[1];
    const float* lift_b  = (const float*)d_in[2];
    const float* w1r     = (const float*)d_in[3];
    const float* w1i     = (const float*)d_in[4];
    const float* w2r     = (const float*)d_in[5];
    const float* w2i     = (const float*)d_in[6];
    const float* skip_w  = (const float*)d_in[7];
    const float* skip_b  = (const float*)d_in[8];
    const float* proj_w1 = (const float*)d_in[9];
    const float* proj_b1 = (const float*)d_in[10];
    const float* proj_w2 = (const float*)d_in[11];
    const float* proj_b2 = (const float*)d_in[12];
    const float* head_w  = (const float*)d_in[13];
    const float* head_b  = (const float*)d_in[14];
    float* out = (float*)d_out;

    u32*    vp   = (u32*)d_ws;                   // 16,777,216 u32 (packed hi|lo v)
    float2* Fw   = (float2*)(vp + 16777216);     // 1,048,576 float2
    float2* vftp = Fw  + 1048576;                // 524,288 float2
    float2* Gh   = vftp + 524288;                // 1,048,576 float2
    float2* Wt2  = Gh  + 1048576;                // 524,288 float2
    float*  poolq = (float*)(Wt2 + 524288);      // 2,048 floats
    unsigned short* Ep  = (unsigned short*)(poolq + 2048);   // 16,384 shorts
    unsigned short* Fp  = Ep + 16384;                        // 32,768 shorts
    unsigned short* skA = Fp + 32768;                        // 4,096 shorts
    unsigned short* W1A = skA + 4096;                        // 4,096 shorts

    fno_prep_k<<<2280, 256, 0, stream>>>(w1r, w1i, w2r, w2i, Wt2,
                                         skip_w, proj_w1, Ep, Fp, skA, W1A, poolq);
    fno_liftf1_k<<<4096, 256, 0, stream>>>(x, lift_w, lift_b, vp, Fw);

    for(int l=0; l<4; l++){
        fno_f2q_k<<<1024, 256, 0, stream>>>(Fw, vftp);
        fno_mixi1_k<<<512, 256, 0, stream>>>(vftp, Wt2, Gh, l);
        if(l < 3){
            fno_layer_k<<<2048, 256, 0, stream>>>(Gh, vp, Ep, Fp, skA, skip_b, Fw, l);
        } else {
            fno_l3proj_k<<<1024, 256, 0, stream>>>(Gh, vp, Ep, skA, skip_b, W1A, proj_b1, poolq);
        }
    }

    fno_head_k<<<1, 1024, 0, stream>>>(poolq, proj_w2, proj_b2, head_w, head_b, out);
}